// Round 16
// baseline (2278.507 us; speedup 1.0000x reference)
//
#include <hip/hip_runtime.h>
#include <math.h>

typedef short s8v __attribute__((ext_vector_type(8)));
typedef short s4v __attribute__((ext_vector_type(4)));
typedef float f4v __attribute__((ext_vector_type(4)));
typedef _Float16 h8v __attribute__((ext_vector_type(8)));

__device__ __forceinline__ float sigf(float x) { return 1.f / (1.f + expf(-x)); }
__device__ __forceinline__ float f16f(short v) {
  return (float)__builtin_bit_cast(_Float16, v);
}

#define SCALE_CLAMP 4.135166556742356f
#define IMG_SIZE 800.f
#define PLANE 14482432ull   // shorts per activation plane: sumPHW(14143)*4*256
#define W_SCALE 1024.f
#define A_SCALE 64.f
#define ACC_RESCALE 1.52587890625e-5f   // 2^-16

// fp16 2-way split (round-to-nearest): x ~= h + l, residual <= 2^-24 |x|
__device__ __forceinline__ void split2(float x, short& h, short& l) {
  _Float16 hf = (_Float16)x;
  _Float16 lf = (_Float16)(x - (float)hf);
  h = __builtin_bit_cast(short, hf);
  l = __builtin_bit_cast(short, lf);
}

struct Geo {
  int tp[6];                 // conv tile prefix per level (4x16 tiles)
  int TXa[5];
  int Ha[5], Wa[5], PWa[5], PHWa[5];
  int phwOff[5];
  int hwOff[5];
  int pb[6];
  int bb[6];
};

// ==================== weight split+transpose (fp16 h/l, x1024) ====================
__global__ __launch_bounds__(256) void wtrans_k(const float* __restrict__ cls_tw,
                                                const float* __restrict__ bbox_tw,
                                                short* __restrict__ wt)
{
  const int total = 589824;
  for (int u = blockIdx.x * 256 + threadIdx.x; u < total; u += gridDim.x * 256) {
    int layer = u / 73728;
    int r = u - layer * 73728;
    int tap = r / 8192;  r -= tap * 8192;
    int cc  = r / 1024;  r -= cc * 1024;
    int qq  = r / 256;   int ko = r - qq * 256;
    int cibase = cc * 32 + qq * 8;
    const float* src = (layer < 4) ? (cls_tw + (size_t)layer * 589824)
                                   : (bbox_tw + (size_t)(layer - 4) * 589824);
    s8v hv, lv;
#pragma unroll
    for (int e = 0; e < 8; ++e) {
      float x = src[(size_t)ko * 2304 + (size_t)(cibase + e) * 9 + tap] * W_SCALE;
      short h, l; split2(x, h, l);
      hv[e] = h; lv[e] = l;
    }
    size_t dbase = (size_t)layer * 1179648 + (((size_t)tap * 8 + cc) * 4 + qq) * 2048 + (size_t)ko * 8;
    *(s8v*)(wt + dbase) = hv;
    *(s8v*)(wt + dbase + 589824) = lv;
  }
}

// ==================== NCHW fp32 -> padded split-plane fp16x2 (x64) ====================
__global__ __launch_bounds__(256) void prep_all_k(const float* __restrict__ p3, const float* __restrict__ p4,
                                                  const float* __restrict__ p5, const float* __restrict__ p6,
                                                  const float* __restrict__ p7,
                                                  short* __restrict__ out, Geo g)
{
  __shared__ float tl[64][260];
  int bx = blockIdx.x, t = threadIdx.x, n = blockIdx.y;
  int l = 0; while (l < 4 && bx >= g.pb[l + 1]) ++l;
  const float* in = (l == 0) ? p3 : (l == 1) ? p4 : (l == 2) ? p5 : (l == 3) ? p6 : p7;
  int H = g.Ha[l], W = g.Wa[l], PW = g.PWa[l], PHW = g.PHWa[l], HW = H * W;
  int P0 = (bx - g.pb[l]) * 64;
  const float* inN = in + (size_t)n * HW * 256;
  int sub = t >> 6, pl = t & 63;
  int pos = P0 + pl;
  for (int i = 0; i < 64; ++i) {
    int ci = i * 4 + sub;
    tl[pl][ci] = (pos < HW) ? inN[(size_t)ci * HW + pos] : 0.f;
  }
  __syncthreads();
  int pl2 = t >> 2, cq = (t & 3) * 64;
  int pos2 = P0 + pl2;
  if (pos2 < HW) {
    int y = pos2 / W, x = pos2 - y * W;
    size_t oo = ((size_t)g.phwOff[l] * 4 + (size_t)n * PHW + (size_t)(y + 1) * PW + (x + 1)) * 256 + cq;
#pragma unroll
    for (int grp = 0; grp < 8; ++grp) {
      s8v hv, lv;
#pragma unroll
      for (int e = 0; e < 8; ++e) {
        short h, lo; split2(tl[pl2][cq + grp * 8 + e] * A_SCALE, h, lo);
        hv[e] = h; lv[e] = lo;
      }
      *(s8v*)(out + oo + grp * 8) = hv;
      *(s8v*)(out + PLANE + oo + grp * 8) = lv;
    }
  }
}

// ==================== MFMA conv 3x3 + bias + relu (fp16, dual-tower capable) ====================
// Grid 8*nT (serial: tower always 0) or 16*nT (fused: tower = wgid/(8*nT... via it>>2)).
// XCD swizzle: wgid = (bid&7)*nhalf + bid>>3, nhalf = 2*nT; it = wgid/nhalf.
#define QS    128
#define PSTR  4096   // shorts per plane (512*8)
#define BSTR  8192   // shorts per buffer (2 planes)
__global__ __launch_bounds__(256, 4) void conv_all_k(const short* __restrict__ in0,
                                                     const short* __restrict__ in1,
                                                     const short* __restrict__ wt0,
                                                     const short* __restrict__ wt1,
                                                     const float* __restrict__ bias0,
                                                     const float* __restrict__ bias1,
                                                     short* __restrict__ out0,
                                                     short* __restrict__ out1, Geo g)
{
  __shared__ short act_s[2 * BSTR];  // 32768 B

  const int t = threadIdx.x;
  const int lane = t & 63, wave = t >> 6;
  const int wcol = wave & 1, wko = wave >> 1;
  const int nT = g.tp[5];
  const int nhalf = 2 * nT;            // blocks per (tower,image)
  int bid = blockIdx.x;
  int wgid = (bid & 7) * nhalf + (bid >> 3);
  const int it = wgid / nhalf;         // tower*4 + image (serial grid: 0..3)
  const int tower = it >> 2;
  const int n = it & 3;
  int r2 = wgid - it * nhalf;
  int bx = r2 >> 1;
  const int ko0 = (r2 & 1) * 128;
  const short* in   = tower ? in1 : in0;
  const short* wtL  = tower ? wt1 : wt0;
  const float* bias = tower ? bias1 : bias0;
  short* out        = tower ? out1 : out0;
  int l = 0; while (l < 4 && bx >= g.tp[l + 1]) ++l;
  const int H = g.Ha[l], W = g.Wa[l], PW = g.PWa[l], PHW = g.PHWa[l];
  const int lt = bx - g.tp[l];
  const int TX = g.TXa[l];
  const int ty = lt / TX, tx = lt - ty * TX;
  const int R0 = ty * 4, C0 = tx * 16;
  const size_t bi = ((size_t)g.phwOff[l] * 4 + (size_t)n * PHW) * 256;
  const short* inN = in + bi;
  short* outN = out + bi;

  const int r = lane & 15, q = lane >> 4;
  const int cb = wcol * 8;
  const short* wlane = wtL + (size_t)q * 2048 + (size_t)(ko0 + wko * 64 + r) * 8;
  const int abase = q * QS + 2 * q + (r >> 3) * 18 + cb + (r & 7);

  int soff[2];
#pragma unroll
  for (int k = 0; k < 2; ++k) {
    int j = t + k * 256;                 // 0..511
    int qq = j >> 7, ppos = j & 127;
    int lpos = ppos - 2 * qq;
    if (lpos < 0) lpos = 0;
    if (lpos > 107) lpos = 107;
    int row = lpos / 18, col = lpos - row * 18;
    int prow = R0 + row; if (prow > H + 1) prow = H + 1;
    int pcol = C0 + col; if (pcol > W + 1) pcol = W + 1;
    soff[k] = (prow * PW + pcol) * 256 + qq * 8;
  }

  f4v acc[2][4];
#pragma unroll
  for (int mi = 0; mi < 2; ++mi)
#pragma unroll
    for (int ni = 0; ni < 4; ++ni) { f4v z = {0.f, 0.f, 0.f, 0.f}; acc[mi][ni] = z; }

  auto stage = [&](int cc, int buf) {
#pragma unroll
    for (int k = 0; k < 2; ++k)
#pragma unroll
      for (int p = 0; p < 2; ++p) {
        const short* src = inN + (size_t)p * PLANE + (size_t)(soff[k] + cc * 32);
        short* dst = &act_s[(size_t)buf * BSTR + (size_t)p * PSTR + (size_t)(t + k * 256) * 8];
#if __has_builtin(__builtin_amdgcn_global_load_lds)
        __builtin_amdgcn_global_load_lds((const __attribute__((address_space(1))) void*)src,
                                         (__attribute__((address_space(3))) void*)dst, 16, 0, 0);
#else
        *(s8v*)dst = *(const s8v*)src;
#endif
      }
  };

  auto loadWT = [&](s8v (&w)[2][4], int cc2, int tap2) {
    const short* base = wlane + (size_t)(tap2 * 8 + cc2) * 8192;
#pragma unroll
    for (int p = 0; p < 2; ++p)
#pragma unroll
      for (int k = 0; k < 4; ++k)
        w[p][k] = *(const s8v*)(base + (size_t)p * 589824 + k * 128);
  };

  auto runTap = [&](const s8v (&w)[2][4], int dy, int dx, int buf) {
    s8v afr[2][2];
    const int b0 = buf * BSTR + abase * 8;
    const int d = (dy * 18 + dx) * 8;
#pragma unroll
    for (int mi = 0; mi < 2; ++mi) {
      afr[0][mi] = *(const s8v*)&act_s[b0 + mi * 288 + d];
      afr[1][mi] = *(const s8v*)&act_s[b0 + PSTR + mi * 288 + d];
    }
    const int PA[3] = {0, 0, 1};
    const int PB[3] = {0, 1, 0};
    __builtin_amdgcn_s_setprio(1);
#pragma unroll
    for (int pp = 0; pp < 3; ++pp)
#pragma unroll
      for (int mi = 0; mi < 2; ++mi)
#pragma unroll
        for (int ni = 0; ni < 4; ++ni)
          acc[mi][ni] = __builtin_amdgcn_mfma_f32_16x16x32_f16(
              __builtin_bit_cast(h8v, afr[PA[pp]][mi]),
              __builtin_bit_cast(h8v, w[PB[pp]][ni]),
              acc[mi][ni], 0, 0, 0);
    __builtin_amdgcn_s_setprio(0);
  };

  s8v wA[2][4], wB[2][4];

  auto ccBody = [&](int cc, int buf, s8v (&wF)[2][4], s8v (&wS)[2][4]) {
    if (cc < 7) stage(cc + 1, buf ^ 1);
#pragma unroll
    for (int tap = 0; tap < 9; ++tap) {
      const int dy = tap / 3, dx = tap - dy * 3;
      int ntap = (tap == 8) ? 0 : tap + 1;
      int ncc  = (tap == 8) ? cc + 1 : cc;
      if ((tap & 1) == 0) {
        if (ncc < 8) loadWT(wS, ncc, ntap);
        __builtin_amdgcn_sched_barrier(0);
        runTap(wF, dy, dx, buf);
      } else {
        if (ncc < 8) loadWT(wF, ncc, ntap);
        __builtin_amdgcn_sched_barrier(0);
        runTap(wS, dy, dx, buf);
      }
    }
    __syncthreads();
  };

  stage(0, 0);
  loadWT(wA, 0, 0);
  __syncthreads();

  int cur = 0;
#pragma unroll
  for (int ccp = 0; ccp < 4; ++ccp) {
    ccBody(2 * ccp, cur, wA, wB);
    cur ^= 1;
    ccBody(2 * ccp + 1, cur, wB, wA);
    cur ^= 1;
  }

#pragma unroll
  for (int mi = 0; mi < 2; ++mi) {
#pragma unroll
    for (int ni = 0; ni < 4; ++ni) {
      int ko = ko0 + wko * 64 + ni * 16 + r;
      float bv = bias[ko];
#pragma unroll
      for (int reg = 0; reg < 4; ++reg) {
        int rm = q * 4 + reg;
        int orow = R0 + 2 * mi + (rm >> 3);
        int ocol = C0 + cb + (rm & 7);
        if (orow < H && ocol < W) {
          float real = acc[mi][ni][reg] * ACC_RESCALE + bv;
          float vv = fmaxf(real, 0.f) * A_SCALE;
          short h, lo; split2(vv, h, lo);
          size_t oo = ((size_t)(orow + 1) * PW + (ocol + 1)) * 256 + ko;
          outN[oo] = h; outN[PLANE + oo] = lo;
        }
      }
    }
  }
}

// ==================== cls head (all levels): 1x1x80 + sigmoid ====================
__global__ __launch_bounds__(256) void cls_head_k(const short* __restrict__ act,
                                                  const float* __restrict__ wcls,
                                                  const float* __restrict__ bcls,
                                                  float* __restrict__ score, Geo g)
{
  __shared__ int   p2s[64];
  __shared__ float as_[64][69];
  __shared__ float ws_[64][84];
  const int t = threadIdx.x;
  const int n = blockIdx.y;
  int bx = blockIdx.x;
  int l = 0; while (l < 4 && bx >= g.pb[l + 1]) ++l;
  const int H = g.Ha[l], W = g.Wa[l], PW = g.PWa[l], PHW = g.PHWa[l], HW = H * W;
  const int P0 = (bx - g.pb[l]) * 64;
  if (t < 64) {
    int p = P0 + t; if (p >= HW) p = HW - 1;
    int y = p / W, x = p - y * W;
    p2s[t] = (y + 1) * PW + x + 1;
  }
  __syncthreads();
  float accv[4][5];
#pragma unroll
  for (int i = 0; i < 4; ++i)
#pragma unroll
    for (int j = 0; j < 5; ++j) accv[i][j] = 0.f;

  const short* actN = act + ((size_t)g.phwOff[l] * 4 + (size_t)n * PHW) * 256;
  const int pg = t >> 4, cg = t & 15;
  const float inv = 1.f / A_SCALE;

  for (int c0 = 0; c0 < 256; c0 += 64) {
    for (int i = t; i < 1024; i += 256) {
      int pos = i >> 4, c4 = i & 15;
      size_t o = (size_t)p2s[pos] * 256 + c0 + c4 * 4;
      s4v hv = *(const s4v*)(actN + o);
      s4v lv = *(const s4v*)(actN + PLANE + o);
      float* dst = &as_[pos][c4 * 4];
#pragma unroll
      for (int e = 0; e < 4; ++e) dst[e] = (f16f(hv[e]) + f16f(lv[e])) * inv;
    }
    for (int i = t; i < 1280; i += 256) {
      int c = i >> 4, c4 = i & 15;
      float4 v = *(const float4*)(wcls + (size_t)c * 256 + c0 + c4 * 4);
      ws_[c4 * 4 + 0][c] = v.x; ws_[c4 * 4 + 1][c] = v.y;
      ws_[c4 * 4 + 2][c] = v.z; ws_[c4 * 4 + 3][c] = v.w;
    }
    __syncthreads();
#pragma unroll 8
    for (int ci = 0; ci < 64; ++ci) {
#pragma unroll
      for (int i = 0; i < 4; ++i) {
        float a = as_[pg * 4 + i][ci];
#pragma unroll
        for (int j = 0; j < 5; ++j)
          accv[i][j] = fmaf(a, ws_[ci][cg * 5 + j], accv[i][j]);
      }
    }
    __syncthreads();
  }
  float* sB = score + ((size_t)g.hwOff[l] * 4 + (size_t)n * HW) * 80;
#pragma unroll
  for (int i = 0; i < 4; ++i) {
    int p = P0 + pg * 4 + i;
    if (p >= HW) continue;
#pragma unroll
    for (int j = 0; j < 5; ++j) {
      int c = cg * 5 + j;
      sB[(size_t)p * 80 + c] = sigf(accv[i][j] + bcls[c]);
    }
  }
}

// ==================== box head (all levels) ====================
__global__ __launch_bounds__(256) void box_head_k(const short* __restrict__ act,
                                                  const float* __restrict__ wbox,
                                                  const float* __restrict__ bb,
                                                  const float* __restrict__ wctr,
                                                  const float* __restrict__ bc,
                                                  const float* __restrict__ scales,
                                                  float* __restrict__ score,
                                                  float* __restrict__ deltas, Geo g)
{
  int n = blockIdx.y;
  int bx = blockIdx.x;
  int l = 0; while (l < 4 && bx >= g.bb[l + 1]) ++l;
  const int H = g.Ha[l], W = g.Wa[l], PW = g.PWa[l], PHW = g.PHWa[l], HW = H * W;
  int p = (bx - g.bb[l]) * 256 + threadIdx.x;
  if (p >= HW) return;
  int y = p / W, x = p - y * W;
  const short* a = act + ((size_t)g.phwOff[l] * 4 + (size_t)n * PHW + (size_t)(y + 1) * PW + x + 1) * 256;
  const float inv = 1.f / A_SCALE;
  float d0 = 0, d1 = 0, d2 = 0, d3 = 0, ct = 0;
  for (int gI = 0; gI < 32; ++gI) {
    s8v hv = *(const s8v*)(a + gI * 8);
    s8v lv = *(const s8v*)(a + PLANE + gI * 8);
#pragma unroll
    for (int e = 0; e < 8; ++e) {
      float av = (f16f(hv[e]) + f16f(lv[e])) * inv;
      int c = gI * 8 + e;
      d0 = fmaf(av, wbox[c], d0);
      d1 = fmaf(av, wbox[256 + c], d1);
      d2 = fmaf(av, wbox[512 + c], d2);
      d3 = fmaf(av, wbox[768 + c], d3);
      ct = fmaf(av, wctr[c], ct);
    }
  }
  float sl = scales[l];
  float* dd = deltas + ((size_t)g.hwOff[l] * 4 + (size_t)n * HW + p) * 4;
  dd[0] = sl * (d0 + bb[0]); dd[1] = sl * (d1 + bb[1]);
  dd[2] = sl * (d2 + bb[2]); dd[3] = sl * (d3 + bb[3]);
  float sct = sigf(ct + bc[0]);
  float* sp = score + ((size_t)g.hwOff[l] * 4 + (size_t)n * HW + p) * 80;
#pragma unroll
  for (int i = 0; i < 20; ++i) {
    float4 v = ((float4*)sp)[i];
    v.x *= sct; v.y *= sct; v.z *= sct; v.w *= sct;
    v.x = (v.x > 0.05f) ? v.x : 0.f;
    v.y = (v.y > 0.05f) ? v.y : 0.f;
    v.z = (v.z > 0.05f) ? v.z : 0.f;
    v.w = (v.w > 0.05f) ? v.w : 0.f;
    ((float4*)sp)[i] = v;
  }
}

// ==================== exact top-1000: 3-pass bit histogram, 20 groups ====================
__global__ __launch_bounds__(256) void hist_k(const float* __restrict__ score,
                                              const unsigned* __restrict__ thr,
                                              unsigned* __restrict__ hist, int phase, Geo g)
{
  const int grp = blockIdx.y;
  const int l = grp >> 2, n = grp & 3;
  const int HW = g.Ha[l] * g.Wa[l];
  const int M = HW * 80;
  const float* s = score + ((size_t)g.hwOff[l] * 4 + (size_t)n * HW) * 80;
  unsigned* h = hist + grp * 2048;
  const unsigned* tr = thr + grp * 8;
  __shared__ unsigned lh[2048];
  for (int i = threadIdx.x; i < 2048; i += 256) lh[i] = 0u;
  __syncthreads();
  unsigned B1 = 0, pref = 0;
  if (phase == 1) B1 = tr[0];
  if (phase == 2) pref = (tr[0] << 11) | tr[1];
  for (int idx = blockIdx.x * 256 + threadIdx.x; idx < M; idx += gridDim.x * 256) {
    float v = s[idx];
    if (v > 0.f) {
      unsigned b = __float_as_uint(v);
      if (phase == 0) atomicAdd(&lh[b >> 20], 1u);
      else if (phase == 1) { if ((b >> 20) == B1) atomicAdd(&lh[(b >> 9) & 0x7FFu], 1u); }
      else { if ((b >> 9) == pref) atomicAdd(&lh[b & 0x1FFu], 1u); }
    }
  }
  __syncthreads();
  for (int i = threadIdx.x; i < 2048; i += 256) { unsigned v = lh[i]; if (v) atomicAdd(&h[i], v); }
}

__global__ __launch_bounds__(256) void scan_k(unsigned* __restrict__ hist,
                                              unsigned* __restrict__ thr, int phase)
{
  const int grp = blockIdx.x, t = threadIdx.x;
  unsigned* h  = hist + grp * 2048;
  unsigned* tr = thr + grp * 8;
  const int nb = (phase == 2) ? 512 : 2048;
  const int PB = nb / 256;
  unsigned target = 1000u;
  bool dead = false;
  if (phase >= 1) {
    target = 1000u - tr[2];
    if (tr[0] == 0xFFFFFFFFu) dead = true;
    if (phase == 2 && tr[1] == 0xFFFFFFFFu) dead = true;
  }
  __shared__ unsigned ps[256];
  __shared__ unsigned s_tot;
  const int hi = nb - t * PB;
  unsigned lsum = 0;
  for (int k = 0; k < PB; ++k) lsum += h[hi - 1 - k];
  ps[t] = lsum;
  __syncthreads();
  if (t == 0) {
    unsigned cum = 0;
    for (int i = 0; i < 256; ++i) { unsigned tmp = ps[i]; ps[i] = cum; cum += tmp; }
    s_tot = cum;
  }
  __syncthreads();
  unsigned exc = ps[t], tot = s_tot;
  if (!dead && tot >= target) {
    if (exc < target && exc + lsum >= target) {
      unsigned cum = exc; int bf = 0; unsigned above = 0;
      for (int k = 0; k < PB; ++k) {
        int bidx = hi - 1 - k;
        unsigned c = h[bidx];
        if (cum < target && cum + c >= target) { bf = bidx; above = cum; }
        cum += c;
      }
      if (phase == 0)      { tr[0] = (unsigned)bf; tr[2] = above; }
      else if (phase == 1) { tr[1] = (unsigned)bf; tr[2] = tr[2] + above; }
      else {
        unsigned T = (tr[0] << 20) | (tr[1] << 9) | (unsigned)bf;
        tr[3] = T; tr[4] = target - above;
      }
    }
  } else if (t == 0) {
    if (phase == 0)      { tr[0] = 0xFFFFFFFFu; tr[2] = 0u; }
    else if (phase == 1) { tr[1] = 0xFFFFFFFFu; }
    else                 { tr[3] = 0u; tr[4] = 0u; }
  }
  if (phase == 2 && t == 0) { tr[5] = 0u; tr[6] = 0u; }
}

// ==================== select + decode ====================
__global__ __launch_bounds__(256) void select_k(const float* __restrict__ score,
                                                const float* __restrict__ deltas,
                                                unsigned* __restrict__ thr,
                                                float* __restrict__ cbox, float* __restrict__ csc,
                                                float* __restrict__ ccls, float* __restrict__ cgid,
                                                Geo g)
{
  const int grp = blockIdx.y;
  const int l = grp >> 2, n = grp & 3;
  const int W = g.Wa[l];
  const int HW = g.Ha[l] * W;
  const int M = HW * 80;
  const float stride_ = (float)(8 << l);
  const float* s = score + ((size_t)g.hwOff[l] * 4 + (size_t)n * HW) * 80;
  const float* dBase = deltas + ((size_t)g.hwOff[l] * 4 + (size_t)n * HW) * 4;
  unsigned* tr = thr + grp * 8;
  const unsigned T = tr[3], need = tr[4];
  for (int idx = blockIdx.x * 256 + threadIdx.x; idx < M; idx += gridDim.x * 256) {
    float v = s[idx];
    if (!(v > 0.f)) continue;
    unsigned b = __float_as_uint(v);
    int slot = -1;
    if (b > T) slot = (int)atomicAdd(&tr[5], 1u);
    else if (b == T) {
      unsigned e = atomicAdd(&tr[6], 1u);
      if (e < need) slot = (int)(1000u - need + e);
    }
    if (slot < 0) continue;
    int p = idx / 80, c = idx - p * 80;
    int y = p / W, x = p - y * W;
    const float* d = dBase + (size_t)p * 4;
    float sz  = 8.f * stride_;
    float acx = ((float)x + 0.5f) * stride_;
    float acy = ((float)y + 0.5f) * stride_;
    float dx = d[0] / 10.f, dy = d[1] / 10.f;
    float dw = fminf(d[2] / 5.f, SCALE_CLAMP);
    float dh = fminf(d[3] / 5.f, SCALE_CLAMP);
    float pcx = dx * sz + acx;
    float pcy = dy * sz + acy;
    float pw = expf(dw) * sz;
    float ph = expf(dh) * sz;
    float x1 = pcx - 0.5f * pw, y1_ = pcy - 0.5f * ph;
    float x2 = pcx + 0.5f * pw, y2_ = pcy + 0.5f * ph;
    x1  = fminf(fmaxf(x1, 0.f),  IMG_SIZE);
    y1_ = fminf(fmaxf(y1_, 0.f), IMG_SIZE);
    x2  = fminf(fmaxf(x2, 0.f),  IMG_SIZE);
    y2_ = fminf(fmaxf(y2_, 0.f), IMG_SIZE);
    int cslot = n * 5000 + l * 1000 + slot;
    ((float4*)cbox)[cslot] = make_float4(x1, y1_, x2, y2_);
    csc[cslot]  = sqrtf(v);
    ccls[cslot] = (float)c;
    cgid[cslot] = (float)(((unsigned)l << 20) | (unsigned)idx);
  }
}

// ==================== NMS stage A: bucket candidates by class (1 block/image) ====================
__global__ __launch_bounds__(256) void nms_bucket_k(const float* __restrict__ cbox,
                                                    const float* __restrict__ csc,
                                                    const float* __restrict__ ccls,
                                                    const float* __restrict__ cgid,
                                                    float4* __restrict__ bbox2,
                                                    unsigned long long* __restrict__ bkey2,
                                                    int* __restrict__ coff)
{
  __shared__ unsigned cnt[80];
  __shared__ unsigned off_s[81];
  const int n = blockIdx.x, t = threadIdx.x;
  for (int i = t; i < 80; i += 256) cnt[i] = 0u;
  __syncthreads();
  for (int i = t; i < 5000; i += 256) {
    float s = csc[n * 5000 + i];
    if (s > 0.f) atomicAdd(&cnt[(int)ccls[n * 5000 + i]], 1u);
  }
  __syncthreads();
  if (t == 0) {
    unsigned c = 0;
    for (int k = 0; k < 80; ++k) { off_s[k] = c; c += cnt[k]; }
    off_s[80] = c;
  }
  __syncthreads();
  for (int i = t; i < 81; i += 256) coff[n * 81 + i] = (int)off_s[i];
  for (int i = t; i < 80; i += 256) cnt[i] = 0u;
  __syncthreads();
  for (int i = t; i < 5000; i += 256) {
    float s = csc[n * 5000 + i];
    if (s > 0.f) {
      int c = (int)ccls[n * 5000 + i];
      unsigned p = atomicAdd(&cnt[c], 1u);
      int dst = n * 5000 + (int)off_s[c] + (int)p;
      bbox2[dst] = ((const float4*)cbox)[n * 5000 + i];
      unsigned long long sb = (unsigned long long)__float_as_uint(s);
      unsigned gid = (unsigned)cgid[n * 5000 + i];
      bkey2[dst] = (sb << 24) | (unsigned long long)(0xFFFFFFu - gid);
    }
  }
}

// ==================== NMS stage B: per-(image,class) sorted-scan greedy, one wave ====================
#define NCAP 1536
__global__ __launch_bounds__(64) void nms_class_k(const float4* __restrict__ bbox2,
                                                  unsigned long long* __restrict__ bkey2,
                                                  const int* __restrict__ coff,
                                                  float4* __restrict__ kbox,
                                                  unsigned long long* __restrict__ kkey,
                                                  int* __restrict__ kcnt)
{
  __shared__ unsigned long long key_s[NCAP];
  __shared__ unsigned long long sk_s[NCAP];
  __shared__ float4 sb_s[NCAP];
  __shared__ unsigned char af_s[NCAP + 64];
  const int cls = blockIdx.x, n = blockIdx.y, t = threadIdx.x;
  const int lo = coff[n * 81 + cls], hi = coff[n * 81 + cls + 1];
  const int c = hi - lo;
  const int base = n * 5000 + lo;
  const int outB = (n * 80 + cls) * 100;
  int kept = 0;
  if (c > 0 && c <= NCAP) {
    const int nch = (c + 63) >> 6;
    for (int i = t; i < nch * 64; i += 64) af_s[i] = 0;
    for (int i = t; i < c; i += 64) key_s[i] = bkey2[base + i];
    __syncthreads();
    for (int i = t; i < c; i += 64) {
      unsigned long long ki = key_s[i];
      int rk = 0;
      for (int m = 0; m < c; ++m) rk += (key_s[m] > ki) ? 1 : 0;
      sk_s[rk] = ki;
      sb_s[rk] = bbox2[base + i];
      af_s[rk] = 1;
    }
    __syncthreads();
    int p = -1;
    while (kept < 100) {
      int np = -1;
      int j0 = (p + 1) >> 6;
      for (int j = j0; j < nch; ++j) {
        int pos = j * 64 + t;
        unsigned long long w = __ballot(af_s[pos] != 0);
        if (j == j0) { int sh = (p + 1) & 63; if (sh) w &= (~0ull) << sh; }
        if (w) { np = j * 64 + (int)__builtin_ctzll(w); break; }
      }
      if (np < 0) break;
      p = np;
      float4 wb = sb_s[p];
      if (t == 0) { kbox[outB + kept] = wb; kkey[outB + kept] = sk_s[p]; }
      ++kept;
      float a1 = (wb.z - wb.x) * (wb.w - wb.y);
      for (int i = p + t; i < c; i += 64) {
        if (!af_s[i]) continue;
        float4 b = sb_s[i];
        float xx1 = fmaxf(wb.x, b.x), yy1 = fmaxf(wb.y, b.y);
        float xx2 = fminf(wb.z, b.z), yy2 = fminf(wb.w, b.w);
        float inter = fmaxf(xx2 - xx1, 0.f) * fmaxf(yy2 - yy1, 0.f);
        float a2 = (b.z - b.x) * (b.w - b.y);
        if (inter / (a1 + a2 - inter + 1e-9f) > 0.6f) af_s[i] = 0;
      }
      __syncthreads();
    }
  } else if (c > NCAP) {
    while (kept < 100) {
      unsigned long long best = 0ull; int bi = 0;
      for (int i = t; i < c; i += 64) {
        unsigned long long k = bkey2[base + i];
        if (k > best) { best = k; bi = i; }
      }
#pragma unroll
      for (int o = 32; o; o >>= 1) {
        unsigned long long ok = __shfl_xor(best, o);
        int oi = __shfl_xor(bi, o);
        if (ok > best) { best = ok; bi = oi; }
      }
      if (best == 0ull) break;
      float4 wb = bbox2[base + bi];
      if (t == 0) { kbox[outB + kept] = wb; kkey[outB + kept] = best; }
      ++kept;
      float a1 = (wb.z - wb.x) * (wb.w - wb.y);
      for (int i = t; i < c; i += 64) {
        unsigned long long k = bkey2[base + i];
        if (!k) continue;
        float4 b = bbox2[base + i];
        float xx1 = fmaxf(wb.x, b.x), yy1 = fmaxf(wb.y, b.y);
        float xx2 = fminf(wb.z, b.z), yy2 = fminf(wb.w, b.w);
        float inter = fmaxf(xx2 - xx1, 0.f) * fmaxf(yy2 - yy1, 0.f);
        float a2 = (b.z - b.x) * (b.w - b.y);
        if (inter / (a1 + a2 - inter + 1e-9f) > 0.6f) bkey2[base + i] = 0ull;
      }
      __syncthreads();
    }
  }
  if (t == 0) kcnt[n * 80 + cls] = kept;
}

// ==================== NMS stage C: 80-way merge (keys preloaded to LDS) ====================
__global__ __launch_bounds__(64) void nms_merge_k(const float4* __restrict__ kbox,
                                                  const unsigned long long* __restrict__ kkey,
                                                  const int* __restrict__ kcnt,
                                                  float* __restrict__ outp)
{
  __shared__ unsigned long long lk[8000];
  __shared__ int head[80];
  __shared__ int cnts[80];
  const int n = blockIdx.x, t = threadIdx.x;
  for (int i = t; i < 80; i += 64) { head[i] = 0; cnts[i] = kcnt[n * 80 + i]; }
  for (int i = t; i < 8000; i += 64) lk[i] = kkey[n * 8000 + i];
  __syncthreads();
  for (int it = 0; it < 100; ++it) {
    unsigned long long best = 0ull; int bc = 0;
    for (int cls = t; cls < 80; cls += 64) {
      int h = head[cls];
      if (h < cnts[cls]) {
        unsigned long long k = lk[cls * 100 + h];
        if (k > best) { best = k; bc = cls; }
      }
    }
#pragma unroll
    for (int o = 32; o; o >>= 1) {
      unsigned long long ok = __shfl_xor(best, o);
      int oc = __shfl_xor(bc, o);
      if (ok > best) { best = ok; bc = oc; }
    }
    if (t == 0) {
      int basei = n * 100 + it;
      if (best != 0ull) {
        int idx = (n * 80 + bc) * 100 + head[bc];
        float4 b = kbox[idx];
        outp[basei * 4 + 0] = b.x; outp[basei * 4 + 1] = b.y;
        outp[basei * 4 + 2] = b.z; outp[basei * 4 + 3] = b.w;
        outp[1600 + basei] = __uint_as_float((unsigned)(best >> 24));
        outp[2000 + basei] = (float)bc;
        head[bc] = head[bc] + 1;
      } else {
        outp[basei * 4 + 0] = 0.f; outp[basei * 4 + 1] = 0.f;
        outp[basei * 4 + 2] = 0.f; outp[basei * 4 + 3] = 0.f;
        outp[1600 + basei] = 0.f;
        outp[2000 + basei] = -1.f;
      }
    }
    __syncthreads();
  }
}

// ==================== host ====================
extern "C" void kernel_launch(void* const* d_in, const int* in_sizes, int n_in,
                              void* d_out, int out_size, void* d_ws, size_t ws_size,
                              hipStream_t stream)
{
  (void)in_sizes; (void)n_in; (void)out_size;
  const float* p3 = (const float*)d_in[0];
  const float* p4 = (const float*)d_in[1];
  const float* p5 = (const float*)d_in[2];
  const float* p6 = (const float*)d_in[3];
  const float* p7 = (const float*)d_in[4];
  const float* cls_tw  = (const float*)d_in[5];
  const float* cls_tb  = (const float*)d_in[6];
  const float* bbox_tw = (const float*)d_in[7];
  const float* bbox_tb = (const float*)d_in[8];
  const float* wcls    = (const float*)d_in[9];
  const float* bcls    = (const float*)d_in[10];
  const float* wbox    = (const float*)d_in[11];
  const float* bbox_b  = (const float*)d_in[12];
  const float* wctr    = (const float*)d_in[13];
  const float* bctr    = (const float*)d_in[14];
  const float* scales  = (const float*)d_in[15];
  float* out = (float*)d_out;

  Geo G;
  const int Hs[5] = {100, 50, 25, 13, 7};
  {
    int tpre = 0, ppre = 0, bpre = 0, phw = 0, hw = 0;
    for (int l = 0; l < 5; ++l) {
      int H = Hs[l], W = Hs[l];
      G.Ha[l] = H; G.Wa[l] = W; G.PWa[l] = W + 2; G.PHWa[l] = (H + 2) * (W + 2);
      G.TXa[l] = (W + 15) / 16;
      int TY = (H + 3) / 4;
      G.tp[l] = tpre;  tpre += G.TXa[l] * TY;
      G.pb[l] = ppre;  ppre += (H * W + 63) / 64;
      G.bb[l] = bpre;  bpre += (H * W + 255) / 256;
      G.phwOff[l] = phw; phw += G.PHWa[l];
      G.hwOff[l]  = hw;  hw  += H * W;
    }
    G.tp[5] = tpre; G.pb[5] = ppre; G.bb[5] = bpre;
  }
  const int nTiles = G.tp[5];   // 247
  const int nPrep  = G.pb[5];   // 211
  const int nBoxB  = G.bb[5];   // 55
  const int sumHW = 13343;
  const size_t scoreBytes  = (size_t)sumHW * 4 * 80 * 4;
  const size_t deltasBytes = (size_t)sumHW * 4 * 4 * 4;

  char* ws = (char*)d_ws;
  size_t off = 0;
  auto alloc = [&](size_t bytes) -> void* {
    off = (off + 255) & ~(size_t)255;
    void* p = ws + off; off += bytes; return p;
  };
  const size_t bufBytes = 2ull * PLANE * 2;   // one fp16 split-plane act buffer = 57.9 MB

  short* wt     = (short*)alloc((size_t)8 * 2 * 589824 * 2);
  float* cbox   = (float*)alloc(4ull * 5000 * 4 * 4);
  float* csc    = (float*)alloc(4ull * 5000 * 4);
  float* ccls   = (float*)alloc(4ull * 5000 * 4);
  float* cgid   = (float*)alloc(4ull * 5000 * 4);
  unsigned* hist = (unsigned*)alloc(20ull * 2048 * 4);
  unsigned* thr  = (unsigned*)alloc(20ull * 8 * 4);
  float4* bbox2 = (float4*)alloc(4ull * 5000 * 16);
  unsigned long long* bkey2 = (unsigned long long*)alloc(4ull * 5000 * 8);
  int* coff     = (int*)alloc(4ull * 81 * 4);
  float4* kbox  = (float4*)alloc(320ull * 100 * 16);
  unsigned long long* kkey = (unsigned long long*)alloc(320ull * 100 * 8);
  int* kcnt     = (int*)alloc(320ull * 4);
  const size_t fixedEnd = (off + 255) & ~(size_t)255;
  // fused needs 4 act buffers (score/deltas alias buffer A, dead after L3)
  const bool fused = (ws_size >= fixedEnd + 4 * (bufBytes + 256) + 8192);

  hipMemsetAsync(csc,  0, 4ull * 5000 * 4, stream);
  hipMemsetAsync(ccls, 0, 4ull * 5000 * 4, stream);
  hipMemsetAsync(cgid, 0, 4ull * 5000 * 4, stream);
  hipMemsetAsync(thr,  0, 20ull * 8 * 4, stream);

  wtrans_k<<<1024, 256, 0, stream>>>(cls_tw, bbox_tw, wt);

  const size_t LSTRIDE = 2ull * 589824;  // shorts per conv layer (2 planes)
  float* score;
  float* deltas;

  if (fused) {
    short* C = (short*)alloc(bufBytes);
    short* A = (short*)alloc(bufBytes);
    short* B = (short*)alloc(bufBytes);
    short* D = (short*)alloc(bufBytes);
    score  = (float*)A;                                     // A dead after L3
    deltas = (float*)((char*)A + ((scoreBytes + 255) & ~(size_t)255));
    hipMemsetAsync(C, 0, bufBytes, stream);
    hipMemsetAsync(A, 0, bufBytes, stream);
    hipMemsetAsync(B, 0, bufBytes, stream);
    hipMemsetAsync(D, 0, bufBytes, stream);

    prep_all_k<<<dim3(nPrep, 4), 256, 0, stream>>>(p3, p4, p5, p6, p7, C, G);
    dim3 cg(16 * nTiles);   // 2 towers x 4 images x nT x 2koG
    conv_all_k<<<cg, 256, 0, stream>>>(C, C, wt + 0 * LSTRIDE, wt + 4 * LSTRIDE,
                                       cls_tb + 0 * 256, bbox_tb + 0 * 256, A, B, G);
    conv_all_k<<<cg, 256, 0, stream>>>(A, B, wt + 1 * LSTRIDE, wt + 5 * LSTRIDE,
                                       cls_tb + 1 * 256, bbox_tb + 1 * 256, C, D, G);
    conv_all_k<<<cg, 256, 0, stream>>>(C, D, wt + 2 * LSTRIDE, wt + 6 * LSTRIDE,
                                       cls_tb + 2 * 256, bbox_tb + 2 * 256, A, B, G);
    conv_all_k<<<cg, 256, 0, stream>>>(A, B, wt + 3 * LSTRIDE, wt + 7 * LSTRIDE,
                                       cls_tb + 3 * 256, bbox_tb + 3 * 256, C, D, G);
    cls_head_k<<<dim3(nPrep, 4), 256, 0, stream>>>(C, wcls, bcls, score, G);
    box_head_k<<<dim3(nBoxB, 4), 256, 0, stream>>>(D, wbox, bbox_b, wctr, bctr, scales,
                                                   score, deltas, G);
  } else {
    // serial fallback (r13-proven): 3 buffers + separate score/deltas (~213 MB)
    short* C = (short*)alloc(bufBytes);
    short* A = (short*)alloc(bufBytes);
    short* B = (short*)alloc(bufBytes);
    score  = (float*)alloc(scoreBytes);
    deltas = (float*)alloc(deltasBytes);
    hipMemsetAsync(C, 0, bufBytes, stream);
    hipMemsetAsync(A, 0, bufBytes, stream);
    hipMemsetAsync(B, 0, bufBytes, stream);

    prep_all_k<<<dim3(nPrep, 4), 256, 0, stream>>>(p3, p4, p5, p6, p7, C, G);
    dim3 cg(8 * nTiles);    // tower bit always 0
    conv_all_k<<<cg, 256, 0, stream>>>(C, C, wt + 0 * LSTRIDE, wt + 0 * LSTRIDE,
                                       cls_tb + 0 * 256, cls_tb + 0 * 256, A, A, G);
    conv_all_k<<<cg, 256, 0, stream>>>(A, A, wt + 1 * LSTRIDE, wt + 1 * LSTRIDE,
                                       cls_tb + 1 * 256, cls_tb + 1 * 256, B, B, G);
    conv_all_k<<<cg, 256, 0, stream>>>(B, B, wt + 2 * LSTRIDE, wt + 2 * LSTRIDE,
                                       cls_tb + 2 * 256, cls_tb + 2 * 256, A, A, G);
    conv_all_k<<<cg, 256, 0, stream>>>(A, A, wt + 3 * LSTRIDE, wt + 3 * LSTRIDE,
                                       cls_tb + 3 * 256, cls_tb + 3 * 256, B, B, G);
    cls_head_k<<<dim3(nPrep, 4), 256, 0, stream>>>(B, wcls, bcls, score, G);
    conv_all_k<<<cg, 256, 0, stream>>>(C, C, wt + 4 * LSTRIDE, wt + 4 * LSTRIDE,
                                       bbox_tb + 0 * 256, bbox_tb + 0 * 256, A, A, G);
    conv_all_k<<<cg, 256, 0, stream>>>(A, A, wt + 5 * LSTRIDE, wt + 5 * LSTRIDE,
                                       bbox_tb + 1 * 256, bbox_tb + 1 * 256, C, C, G);
    conv_all_k<<<cg, 256, 0, stream>>>(C, C, wt + 6 * LSTRIDE, wt + 6 * LSTRIDE,
                                       bbox_tb + 2 * 256, bbox_tb + 2 * 256, A, A, G);
    conv_all_k<<<cg, 256, 0, stream>>>(A, A, wt + 7 * LSTRIDE, wt + 7 * LSTRIDE,
                                       bbox_tb + 3 * 256, bbox_tb + 3 * 256, C, C, G);
    box_head_k<<<dim3(nBoxB, 4), 256, 0, stream>>>(C, wbox, bbox_b, wctr, bctr, scales,
                                                   score, deltas, G);
  }

  // exact top-1000 per (level, image)
  const int hb = 196;
  for (int phase = 0; phase < 3; ++phase) {
    hipMemsetAsync(hist, 0, 20ull * 2048 * 4, stream);
    hist_k<<<dim3(hb, 20), 256, 0, stream>>>(score, thr, hist, phase, G);
    scan_k<<<20, 256, 0, stream>>>(hist, thr, phase);
  }
  select_k<<<dim3(hb, 20), 256, 0, stream>>>(score, deltas, thr, cbox, csc, ccls, cgid, G);

  // NMS: bucket -> per-class sorted-scan greedy (320 waves) -> 80-way merge
  nms_bucket_k<<<4, 256, 0, stream>>>(cbox, csc, ccls, cgid, bbox2, bkey2, coff);
  nms_class_k<<<dim3(80, 4), 64, 0, stream>>>(bbox2, bkey2, coff, kbox, kkey, kcnt);
  nms_merge_k<<<4, 64, 0, stream>>>(kbox, kkey, kcnt, out);
}

// Round 18
// 2270.118 us; speedup vs baseline: 1.0037x; 1.0037x over previous
//
#include <hip/hip_runtime.h>
#include <math.h>

typedef short s8v __attribute__((ext_vector_type(8)));
typedef short s4v __attribute__((ext_vector_type(4)));
typedef float f4v __attribute__((ext_vector_type(4)));
typedef _Float16 h8v __attribute__((ext_vector_type(8)));

__device__ __forceinline__ float sigf(float x) { return 1.f / (1.f + expf(-x)); }
__device__ __forceinline__ float f16f(short v) {
  return (float)__builtin_bit_cast(_Float16, v);
}

#define SCALE_CLAMP 4.135166556742356f
#define IMG_SIZE 800.f
#define PLANE 14482432ull   // shorts per activation plane: sumPHW(14143)*4*256
#define W_SCALE 1024.f
#define A_SCALE 64.f
#define ACC_RESCALE 1.52587890625e-5f   // 2^-16

// fp16 2-way split (round-to-nearest): x ~= h + l, residual <= 2^-24 |x|
__device__ __forceinline__ void split2(float x, short& h, short& l) {
  _Float16 hf = (_Float16)x;
  _Float16 lf = (_Float16)(x - (float)hf);
  h = __builtin_bit_cast(short, hf);
  l = __builtin_bit_cast(short, lf);
}

struct Geo {
  int tp[6];                 // conv tile prefix per level (4x16 tiles)
  int TXa[5];
  int Ha[5], Wa[5], PWa[5], PHWa[5];
  int phwOff[5];
  int hwOff[5];
  int pb[6];
  int bb[6];
};

// ==================== weight split+transpose (fp16 h/l, x1024) ====================
__global__ __launch_bounds__(256) void wtrans_k(const float* __restrict__ cls_tw,
                                                const float* __restrict__ bbox_tw,
                                                short* __restrict__ wt)
{
  const int total = 589824;
  for (int u = blockIdx.x * 256 + threadIdx.x; u < total; u += gridDim.x * 256) {
    int layer = u / 73728;
    int r = u - layer * 73728;
    int tap = r / 8192;  r -= tap * 8192;
    int cc  = r / 1024;  r -= cc * 1024;
    int qq  = r / 256;   int ko = r - qq * 256;
    int cibase = cc * 32 + qq * 8;
    const float* src = (layer < 4) ? (cls_tw + (size_t)layer * 589824)
                                   : (bbox_tw + (size_t)(layer - 4) * 589824);
    s8v hv, lv;
#pragma unroll
    for (int e = 0; e < 8; ++e) {
      float x = src[(size_t)ko * 2304 + (size_t)(cibase + e) * 9 + tap] * W_SCALE;
      short h, l; split2(x, h, l);
      hv[e] = h; lv[e] = l;
    }
    size_t dbase = (size_t)layer * 1179648 + (((size_t)tap * 8 + cc) * 4 + qq) * 2048 + (size_t)ko * 8;
    *(s8v*)(wt + dbase) = hv;
    *(s8v*)(wt + dbase + 589824) = lv;
  }
}

// ==================== NCHW fp32 -> padded split-plane fp16x2 (x64) ====================
__global__ __launch_bounds__(256) void prep_all_k(const float* __restrict__ p3, const float* __restrict__ p4,
                                                  const float* __restrict__ p5, const float* __restrict__ p6,
                                                  const float* __restrict__ p7,
                                                  short* __restrict__ out, Geo g)
{
  __shared__ float tl[64][260];
  int bx = blockIdx.x, t = threadIdx.x, n = blockIdx.y;
  int l = 0; while (l < 4 && bx >= g.pb[l + 1]) ++l;
  const float* in = (l == 0) ? p3 : (l == 1) ? p4 : (l == 2) ? p5 : (l == 3) ? p6 : p7;
  int H = g.Ha[l], W = g.Wa[l], PW = g.PWa[l], PHW = g.PHWa[l], HW = H * W;
  int P0 = (bx - g.pb[l]) * 64;
  const float* inN = in + (size_t)n * HW * 256;
  int sub = t >> 6, pl = t & 63;
  int pos = P0 + pl;
  for (int i = 0; i < 64; ++i) {
    int ci = i * 4 + sub;
    tl[pl][ci] = (pos < HW) ? inN[(size_t)ci * HW + pos] : 0.f;
  }
  __syncthreads();
  int pl2 = t >> 2, cq = (t & 3) * 64;
  int pos2 = P0 + pl2;
  if (pos2 < HW) {
    int y = pos2 / W, x = pos2 - y * W;
    size_t oo = ((size_t)g.phwOff[l] * 4 + (size_t)n * PHW + (size_t)(y + 1) * PW + (x + 1)) * 256 + cq;
#pragma unroll
    for (int grp = 0; grp < 8; ++grp) {
      s8v hv, lv;
#pragma unroll
      for (int e = 0; e < 8; ++e) {
        short h, lo; split2(tl[pl2][cq + grp * 8 + e] * A_SCALE, h, lo);
        hv[e] = h; lv[e] = lo;
      }
      *(s8v*)(out + oo + grp * 8) = hv;
      *(s8v*)(out + PLANE + oo + grp * 8) = lv;
    }
  }
}

// ==================== MFMA conv 3x3 + bias + relu (fp16 16x16x32, 3 products) ====================
// r13/r14-proven serial configuration: 1976 blocks (4 imgs x 247 tiles x 2 koG),
// bijective XCD swizzle wgid = (bid&7)*nT + (bid>>3)  [stride nT: r17's nhalf-stride
// bug made n reach 7 -> OOB], full-tap weight prefetch, sched_barrier load pin.
#define QS    128
#define PSTR  4096   // shorts per plane (512*8)
#define BSTR  8192   // shorts per buffer (2 planes)
__global__ __launch_bounds__(256, 4) void conv_all_k(const short* __restrict__ in0,
                                                     const short* __restrict__ wtL,
                                                     const float* __restrict__ bias,
                                                     short* __restrict__ out0, Geo g)
{
  __shared__ short act_s[2 * BSTR];  // 32768 B

  const int t = threadIdx.x;
  const int lane = t & 63, wave = t >> 6;
  const int wcol = wave & 1, wko = wave >> 1;
  const int nT = g.tp[5];
  int bid = blockIdx.x;
  int wgid = (bid & 7) * nT + (bid >> 3);   // bijective on [0, 8*nT)
  const int n = wgid / (2 * nT);            // image 0..3
  int r2 = wgid - n * (2 * nT);
  int bx = r2 >> 1;
  const int ko0 = (r2 & 1) * 128;
  int l = 0; while (l < 4 && bx >= g.tp[l + 1]) ++l;
  const int H = g.Ha[l], W = g.Wa[l], PW = g.PWa[l], PHW = g.PHWa[l];
  const int lt = bx - g.tp[l];
  const int TX = g.TXa[l];
  const int ty = lt / TX, tx = lt - ty * TX;
  const int R0 = ty * 4, C0 = tx * 16;
  const size_t bi = ((size_t)g.phwOff[l] * 4 + (size_t)n * PHW) * 256;
  const short* inN = in0 + bi;
  short* outN = out0 + bi;

  const int r = lane & 15, q = lane >> 4;
  const int cb = wcol * 8;
  const short* wlane = wtL + (size_t)q * 2048 + (size_t)(ko0 + wko * 64 + r) * 8;
  const int abase = q * QS + 2 * q + (r >> 3) * 18 + cb + (r & 7);

  int soff[2];
#pragma unroll
  for (int k = 0; k < 2; ++k) {
    int j = t + k * 256;                 // 0..511
    int qq = j >> 7, ppos = j & 127;
    int lpos = ppos - 2 * qq;
    if (lpos < 0) lpos = 0;
    if (lpos > 107) lpos = 107;
    int row = lpos / 18, col = lpos - row * 18;
    int prow = R0 + row; if (prow > H + 1) prow = H + 1;
    int pcol = C0 + col; if (pcol > W + 1) pcol = W + 1;
    soff[k] = (prow * PW + pcol) * 256 + qq * 8;
  }

  f4v acc[2][4];
#pragma unroll
  for (int mi = 0; mi < 2; ++mi)
#pragma unroll
    for (int ni = 0; ni < 4; ++ni) { f4v z = {0.f, 0.f, 0.f, 0.f}; acc[mi][ni] = z; }

  auto stage = [&](int cc, int buf) {
#pragma unroll
    for (int k = 0; k < 2; ++k)
#pragma unroll
      for (int p = 0; p < 2; ++p) {
        const short* src = inN + (size_t)p * PLANE + (size_t)(soff[k] + cc * 32);
        short* dst = &act_s[(size_t)buf * BSTR + (size_t)p * PSTR + (size_t)(t + k * 256) * 8];
#if __has_builtin(__builtin_amdgcn_global_load_lds)
        __builtin_amdgcn_global_load_lds((const __attribute__((address_space(1))) void*)src,
                                         (__attribute__((address_space(3))) void*)dst, 16, 0, 0);
#else
        *(s8v*)dst = *(const s8v*)src;
#endif
      }
  };

  auto loadWT = [&](s8v (&w)[2][4], int cc2, int tap2) {
    const short* base = wlane + (size_t)(tap2 * 8 + cc2) * 8192;
#pragma unroll
    for (int p = 0; p < 2; ++p)
#pragma unroll
      for (int k = 0; k < 4; ++k)
        w[p][k] = *(const s8v*)(base + (size_t)p * 589824 + k * 128);
  };

  auto runTap = [&](const s8v (&w)[2][4], int dy, int dx, int buf) {
    s8v afr[2][2];
    const int b0 = buf * BSTR + abase * 8;
    const int d = (dy * 18 + dx) * 8;
#pragma unroll
    for (int mi = 0; mi < 2; ++mi) {
      afr[0][mi] = *(const s8v*)&act_s[b0 + mi * 288 + d];
      afr[1][mi] = *(const s8v*)&act_s[b0 + PSTR + mi * 288 + d];
    }
    const int PA[3] = {0, 0, 1};
    const int PB[3] = {0, 1, 0};
    __builtin_amdgcn_s_setprio(1);
#pragma unroll
    for (int pp = 0; pp < 3; ++pp)
#pragma unroll
      for (int mi = 0; mi < 2; ++mi)
#pragma unroll
        for (int ni = 0; ni < 4; ++ni)
          acc[mi][ni] = __builtin_amdgcn_mfma_f32_16x16x32_f16(
              __builtin_bit_cast(h8v, afr[PA[pp]][mi]),
              __builtin_bit_cast(h8v, w[PB[pp]][ni]),
              acc[mi][ni], 0, 0, 0);
    __builtin_amdgcn_s_setprio(0);
  };

  s8v wA[2][4], wB[2][4];

  auto ccBody = [&](int cc, int buf, s8v (&wF)[2][4], s8v (&wS)[2][4]) {
    if (cc < 7) stage(cc + 1, buf ^ 1);
#pragma unroll
    for (int tap = 0; tap < 9; ++tap) {
      const int dy = tap / 3, dx = tap - dy * 3;
      int ntap = (tap == 8) ? 0 : tap + 1;
      int ncc  = (tap == 8) ? cc + 1 : cc;
      if ((tap & 1) == 0) {
        if (ncc < 8) loadWT(wS, ncc, ntap);
        __builtin_amdgcn_sched_barrier(0);
        runTap(wF, dy, dx, buf);
      } else {
        if (ncc < 8) loadWT(wF, ncc, ntap);
        __builtin_amdgcn_sched_barrier(0);
        runTap(wS, dy, dx, buf);
      }
    }
    __syncthreads();
  };

  stage(0, 0);
  loadWT(wA, 0, 0);
  __syncthreads();

  int cur = 0;
#pragma unroll
  for (int ccp = 0; ccp < 4; ++ccp) {
    ccBody(2 * ccp, cur, wA, wB);
    cur ^= 1;
    ccBody(2 * ccp + 1, cur, wB, wA);
    cur ^= 1;
  }

#pragma unroll
  for (int mi = 0; mi < 2; ++mi) {
#pragma unroll
    for (int ni = 0; ni < 4; ++ni) {
      int ko = ko0 + wko * 64 + ni * 16 + r;
      float bv = bias[ko];
#pragma unroll
      for (int reg = 0; reg < 4; ++reg) {
        int rm = q * 4 + reg;
        int orow = R0 + 2 * mi + (rm >> 3);
        int ocol = C0 + cb + (rm & 7);
        if (orow < H && ocol < W) {
          float real = acc[mi][ni][reg] * ACC_RESCALE + bv;
          float vv = fmaxf(real, 0.f) * A_SCALE;
          short h, lo; split2(vv, h, lo);
          size_t oo = ((size_t)(orow + 1) * PW + (ocol + 1)) * 256 + ko;
          outN[oo] = h; outN[PLANE + oo] = lo;
        }
      }
    }
  }
}

// ==================== cls head (all levels): 1x1x80 + sigmoid ====================
__global__ __launch_bounds__(256) void cls_head_k(const short* __restrict__ act,
                                                  const float* __restrict__ wcls,
                                                  const float* __restrict__ bcls,
                                                  float* __restrict__ score, Geo g)
{
  __shared__ int   p2s[64];
  __shared__ float as_[64][69];
  __shared__ float ws_[64][84];
  const int t = threadIdx.x;
  const int n = blockIdx.y;
  int bx = blockIdx.x;
  int l = 0; while (l < 4 && bx >= g.pb[l + 1]) ++l;
  const int H = g.Ha[l], W = g.Wa[l], PW = g.PWa[l], PHW = g.PHWa[l], HW = H * W;
  const int P0 = (bx - g.pb[l]) * 64;
  if (t < 64) {
    int p = P0 + t; if (p >= HW) p = HW - 1;
    int y = p / W, x = p - y * W;
    p2s[t] = (y + 1) * PW + x + 1;
  }
  __syncthreads();
  float accv[4][5];
#pragma unroll
  for (int i = 0; i < 4; ++i)
#pragma unroll
    for (int j = 0; j < 5; ++j) accv[i][j] = 0.f;

  const short* actN = act + ((size_t)g.phwOff[l] * 4 + (size_t)n * PHW) * 256;
  const int pg = t >> 4, cg = t & 15;
  const float inv = 1.f / A_SCALE;

  for (int c0 = 0; c0 < 256; c0 += 64) {
    for (int i = t; i < 1024; i += 256) {
      int pos = i >> 4, c4 = i & 15;
      size_t o = (size_t)p2s[pos] * 256 + c0 + c4 * 4;
      s4v hv = *(const s4v*)(actN + o);
      s4v lv = *(const s4v*)(actN + PLANE + o);
      float* dst = &as_[pos][c4 * 4];
#pragma unroll
      for (int e = 0; e < 4; ++e) dst[e] = (f16f(hv[e]) + f16f(lv[e])) * inv;
    }
    for (int i = t; i < 1280; i += 256) {
      int c = i >> 4, c4 = i & 15;
      float4 v = *(const float4*)(wcls + (size_t)c * 256 + c0 + c4 * 4);
      ws_[c4 * 4 + 0][c] = v.x; ws_[c4 * 4 + 1][c] = v.y;
      ws_[c4 * 4 + 2][c] = v.z; ws_[c4 * 4 + 3][c] = v.w;
    }
    __syncthreads();
#pragma unroll 8
    for (int ci = 0; ci < 64; ++ci) {
#pragma unroll
      for (int i = 0; i < 4; ++i) {
        float a = as_[pg * 4 + i][ci];
#pragma unroll
        for (int j = 0; j < 5; ++j)
          accv[i][j] = fmaf(a, ws_[ci][cg * 5 + j], accv[i][j]);
      }
    }
    __syncthreads();
  }
  float* sB = score + ((size_t)g.hwOff[l] * 4 + (size_t)n * HW) * 80;
#pragma unroll
  for (int i = 0; i < 4; ++i) {
    int p = P0 + pg * 4 + i;
    if (p >= HW) continue;
#pragma unroll
    for (int j = 0; j < 5; ++j) {
      int c = cg * 5 + j;
      sB[(size_t)p * 80 + c] = sigf(accv[i][j] + bcls[c]);
    }
  }
}

// ==================== box head (all levels) ====================
__global__ __launch_bounds__(256) void box_head_k(const short* __restrict__ act,
                                                  const float* __restrict__ wbox,
                                                  const float* __restrict__ bb,
                                                  const float* __restrict__ wctr,
                                                  const float* __restrict__ bc,
                                                  const float* __restrict__ scales,
                                                  float* __restrict__ score,
                                                  float* __restrict__ deltas, Geo g)
{
  int n = blockIdx.y;
  int bx = blockIdx.x;
  int l = 0; while (l < 4 && bx >= g.bb[l + 1]) ++l;
  const int H = g.Ha[l], W = g.Wa[l], PW = g.PWa[l], PHW = g.PHWa[l], HW = H * W;
  int p = (bx - g.bb[l]) * 256 + threadIdx.x;
  if (p >= HW) return;
  int y = p / W, x = p - y * W;
  const short* a = act + ((size_t)g.phwOff[l] * 4 + (size_t)n * PHW + (size_t)(y + 1) * PW + x + 1) * 256;
  const float inv = 1.f / A_SCALE;
  float d0 = 0, d1 = 0, d2 = 0, d3 = 0, ct = 0;
  for (int gI = 0; gI < 32; ++gI) {
    s8v hv = *(const s8v*)(a + gI * 8);
    s8v lv = *(const s8v*)(a + PLANE + gI * 8);
#pragma unroll
    for (int e = 0; e < 8; ++e) {
      float av = (f16f(hv[e]) + f16f(lv[e])) * inv;
      int c = gI * 8 + e;
      d0 = fmaf(av, wbox[c], d0);
      d1 = fmaf(av, wbox[256 + c], d1);
      d2 = fmaf(av, wbox[512 + c], d2);
      d3 = fmaf(av, wbox[768 + c], d3);
      ct = fmaf(av, wctr[c], ct);
    }
  }
  float sl = scales[l];
  float* dd = deltas + ((size_t)g.hwOff[l] * 4 + (size_t)n * HW + p) * 4;
  dd[0] = sl * (d0 + bb[0]); dd[1] = sl * (d1 + bb[1]);
  dd[2] = sl * (d2 + bb[2]); dd[3] = sl * (d3 + bb[3]);
  float sct = sigf(ct + bc[0]);
  float* sp = score + ((size_t)g.hwOff[l] * 4 + (size_t)n * HW + p) * 80;
#pragma unroll
  for (int i = 0; i < 20; ++i) {
    float4 v = ((float4*)sp)[i];
    v.x *= sct; v.y *= sct; v.z *= sct; v.w *= sct;
    v.x = (v.x > 0.05f) ? v.x : 0.f;
    v.y = (v.y > 0.05f) ? v.y : 0.f;
    v.z = (v.z > 0.05f) ? v.z : 0.f;
    v.w = (v.w > 0.05f) ? v.w : 0.f;
    ((float4*)sp)[i] = v;
  }
}

// ==================== exact top-1000: 3-pass bit histogram, 20 groups ====================
__global__ __launch_bounds__(256) void hist_k(const float* __restrict__ score,
                                              const unsigned* __restrict__ thr,
                                              unsigned* __restrict__ hist, int phase, Geo g)
{
  const int grp = blockIdx.y;
  const int l = grp >> 2, n = grp & 3;
  const int HW = g.Ha[l] * g.Wa[l];
  const int M = HW * 80;
  const float* s = score + ((size_t)g.hwOff[l] * 4 + (size_t)n * HW) * 80;
  unsigned* h = hist + grp * 2048;
  const unsigned* tr = thr + grp * 8;
  __shared__ unsigned lh[2048];
  for (int i = threadIdx.x; i < 2048; i += 256) lh[i] = 0u;
  __syncthreads();
  unsigned B1 = 0, pref = 0;
  if (phase == 1) B1 = tr[0];
  if (phase == 2) pref = (tr[0] << 11) | tr[1];
  for (int idx = blockIdx.x * 256 + threadIdx.x; idx < M; idx += gridDim.x * 256) {
    float v = s[idx];
    if (v > 0.f) {
      unsigned b = __float_as_uint(v);
      if (phase == 0) atomicAdd(&lh[b >> 20], 1u);
      else if (phase == 1) { if ((b >> 20) == B1) atomicAdd(&lh[(b >> 9) & 0x7FFu], 1u); }
      else { if ((b >> 9) == pref) atomicAdd(&lh[b & 0x1FFu], 1u); }
    }
  }
  __syncthreads();
  for (int i = threadIdx.x; i < 2048; i += 256) { unsigned v = lh[i]; if (v) atomicAdd(&h[i], v); }
}

__global__ __launch_bounds__(256) void scan_k(unsigned* __restrict__ hist,
                                              unsigned* __restrict__ thr, int phase)
{
  const int grp = blockIdx.x, t = threadIdx.x;
  unsigned* h  = hist + grp * 2048;
  unsigned* tr = thr + grp * 8;
  const int nb = (phase == 2) ? 512 : 2048;
  const int PB = nb / 256;
  unsigned target = 1000u;
  bool dead = false;
  if (phase >= 1) {
    target = 1000u - tr[2];
    if (tr[0] == 0xFFFFFFFFu) dead = true;
    if (phase == 2 && tr[1] == 0xFFFFFFFFu) dead = true;
  }
  __shared__ unsigned ps[256];
  __shared__ unsigned s_tot;
  const int hi = nb - t * PB;
  unsigned lsum = 0;
  for (int k = 0; k < PB; ++k) lsum += h[hi - 1 - k];
  ps[t] = lsum;
  __syncthreads();
  if (t == 0) {
    unsigned cum = 0;
    for (int i = 0; i < 256; ++i) { unsigned tmp = ps[i]; ps[i] = cum; cum += tmp; }
    s_tot = cum;
  }
  __syncthreads();
  unsigned exc = ps[t], tot = s_tot;
  if (!dead && tot >= target) {
    if (exc < target && exc + lsum >= target) {
      unsigned cum = exc; int bf = 0; unsigned above = 0;
      for (int k = 0; k < PB; ++k) {
        int bidx = hi - 1 - k;
        unsigned c = h[bidx];
        if (cum < target && cum + c >= target) { bf = bidx; above = cum; }
        cum += c;
      }
      if (phase == 0)      { tr[0] = (unsigned)bf; tr[2] = above; }
      else if (phase == 1) { tr[1] = (unsigned)bf; tr[2] = tr[2] + above; }
      else {
        unsigned T = (tr[0] << 20) | (tr[1] << 9) | (unsigned)bf;
        tr[3] = T; tr[4] = target - above;
      }
    }
  } else if (t == 0) {
    if (phase == 0)      { tr[0] = 0xFFFFFFFFu; tr[2] = 0u; }
    else if (phase == 1) { tr[1] = 0xFFFFFFFFu; }
    else                 { tr[3] = 0u; tr[4] = 0u; }
  }
  if (phase == 2 && t == 0) { tr[5] = 0u; tr[6] = 0u; }
}

// ==================== select + decode ====================
__global__ __launch_bounds__(256) void select_k(const float* __restrict__ score,
                                                const float* __restrict__ deltas,
                                                unsigned* __restrict__ thr,
                                                float* __restrict__ cbox, float* __restrict__ csc,
                                                float* __restrict__ ccls, float* __restrict__ cgid,
                                                Geo g)
{
  const int grp = blockIdx.y;
  const int l = grp >> 2, n = grp & 3;
  const int W = g.Wa[l];
  const int HW = g.Ha[l] * W;
  const int M = HW * 80;
  const float stride_ = (float)(8 << l);
  const float* s = score + ((size_t)g.hwOff[l] * 4 + (size_t)n * HW) * 80;
  const float* dBase = deltas + ((size_t)g.hwOff[l] * 4 + (size_t)n * HW) * 4;
  unsigned* tr = thr + grp * 8;
  const unsigned T = tr[3], need = tr[4];
  for (int idx = blockIdx.x * 256 + threadIdx.x; idx < M; idx += gridDim.x * 256) {
    float v = s[idx];
    if (!(v > 0.f)) continue;
    unsigned b = __float_as_uint(v);
    int slot = -1;
    if (b > T) slot = (int)atomicAdd(&tr[5], 1u);
    else if (b == T) {
      unsigned e = atomicAdd(&tr[6], 1u);
      if (e < need) slot = (int)(1000u - need + e);
    }
    if (slot < 0) continue;
    int p = idx / 80, c = idx - p * 80;
    int y = p / W, x = p - y * W;
    const float* d = dBase + (size_t)p * 4;
    float sz  = 8.f * stride_;
    float acx = ((float)x + 0.5f) * stride_;
    float acy = ((float)y + 0.5f) * stride_;
    float dx = d[0] / 10.f, dy = d[1] / 10.f;
    float dw = fminf(d[2] / 5.f, SCALE_CLAMP);
    float dh = fminf(d[3] / 5.f, SCALE_CLAMP);
    float pcx = dx * sz + acx;
    float pcy = dy * sz + acy;
    float pw = expf(dw) * sz;
    float ph = expf(dh) * sz;
    float x1 = pcx - 0.5f * pw, y1_ = pcy - 0.5f * ph;
    float x2 = pcx + 0.5f * pw, y2_ = pcy + 0.5f * ph;
    x1  = fminf(fmaxf(x1, 0.f),  IMG_SIZE);
    y1_ = fminf(fmaxf(y1_, 0.f), IMG_SIZE);
    x2  = fminf(fmaxf(x2, 0.f),  IMG_SIZE);
    y2_ = fminf(fmaxf(y2_, 0.f), IMG_SIZE);
    int cslot = n * 5000 + l * 1000 + slot;
    ((float4*)cbox)[cslot] = make_float4(x1, y1_, x2, y2_);
    csc[cslot]  = sqrtf(v);
    ccls[cslot] = (float)c;
    cgid[cslot] = (float)(((unsigned)l << 20) | (unsigned)idx);
  }
}

// ==================== NMS stage A: bucket candidates by class (1 block/image) ====================
__global__ __launch_bounds__(256) void nms_bucket_k(const float* __restrict__ cbox,
                                                    const float* __restrict__ csc,
                                                    const float* __restrict__ ccls,
                                                    const float* __restrict__ cgid,
                                                    float4* __restrict__ bbox2,
                                                    unsigned long long* __restrict__ bkey2,
                                                    int* __restrict__ coff)
{
  __shared__ unsigned cnt[80];
  __shared__ unsigned off_s[81];
  const int n = blockIdx.x, t = threadIdx.x;
  for (int i = t; i < 80; i += 256) cnt[i] = 0u;
  __syncthreads();
  for (int i = t; i < 5000; i += 256) {
    float s = csc[n * 5000 + i];
    if (s > 0.f) atomicAdd(&cnt[(int)ccls[n * 5000 + i]], 1u);
  }
  __syncthreads();
  if (t == 0) {
    unsigned c = 0;
    for (int k = 0; k < 80; ++k) { off_s[k] = c; c += cnt[k]; }
    off_s[80] = c;
  }
  __syncthreads();
  for (int i = t; i < 81; i += 256) coff[n * 81 + i] = (int)off_s[i];
  for (int i = t; i < 80; i += 256) cnt[i] = 0u;
  __syncthreads();
  for (int i = t; i < 5000; i += 256) {
    float s = csc[n * 5000 + i];
    if (s > 0.f) {
      int c = (int)ccls[n * 5000 + i];
      unsigned p = atomicAdd(&cnt[c], 1u);
      int dst = n * 5000 + (int)off_s[c] + (int)p;
      bbox2[dst] = ((const float4*)cbox)[n * 5000 + i];
      unsigned long long sb = (unsigned long long)__float_as_uint(s);
      unsigned gid = (unsigned)cgid[n * 5000 + i];
      bkey2[dst] = (sb << 24) | (unsigned long long)(0xFFFFFFu - gid);
    }
  }
}

// ==================== NMS stage B: per-(image,class) sorted-scan greedy, one wave ====================
#define NCAP 1536
__global__ __launch_bounds__(64) void nms_class_k(const float4* __restrict__ bbox2,
                                                  unsigned long long* __restrict__ bkey2,
                                                  const int* __restrict__ coff,
                                                  float4* __restrict__ kbox,
                                                  unsigned long long* __restrict__ kkey,
                                                  int* __restrict__ kcnt)
{
  __shared__ unsigned long long key_s[NCAP];
  __shared__ unsigned long long sk_s[NCAP];
  __shared__ float4 sb_s[NCAP];
  __shared__ unsigned char af_s[NCAP + 64];
  const int cls = blockIdx.x, n = blockIdx.y, t = threadIdx.x;
  const int lo = coff[n * 81 + cls], hi = coff[n * 81 + cls + 1];
  const int c = hi - lo;
  const int base = n * 5000 + lo;
  const int outB = (n * 80 + cls) * 100;
  int kept = 0;
  if (c > 0 && c <= NCAP) {
    const int nch = (c + 63) >> 6;
    for (int i = t; i < nch * 64; i += 64) af_s[i] = 0;
    for (int i = t; i < c; i += 64) key_s[i] = bkey2[base + i];
    __syncthreads();
    for (int i = t; i < c; i += 64) {
      unsigned long long ki = key_s[i];
      int rk = 0;
      for (int m = 0; m < c; ++m) rk += (key_s[m] > ki) ? 1 : 0;
      sk_s[rk] = ki;
      sb_s[rk] = bbox2[base + i];
      af_s[rk] = 1;
    }
    __syncthreads();
    int p = -1;
    while (kept < 100) {
      int np = -1;
      int j0 = (p + 1) >> 6;
      for (int j = j0; j < nch; ++j) {
        int pos = j * 64 + t;
        unsigned long long w = __ballot(af_s[pos] != 0);
        if (j == j0) { int sh = (p + 1) & 63; if (sh) w &= (~0ull) << sh; }
        if (w) { np = j * 64 + (int)__builtin_ctzll(w); break; }
      }
      if (np < 0) break;
      p = np;
      float4 wb = sb_s[p];
      if (t == 0) { kbox[outB + kept] = wb; kkey[outB + kept] = sk_s[p]; }
      ++kept;
      float a1 = (wb.z - wb.x) * (wb.w - wb.y);
      for (int i = p + t; i < c; i += 64) {
        if (!af_s[i]) continue;
        float4 b = sb_s[i];
        float xx1 = fmaxf(wb.x, b.x), yy1 = fmaxf(wb.y, b.y);
        float xx2 = fminf(wb.z, b.z), yy2 = fminf(wb.w, b.w);
        float inter = fmaxf(xx2 - xx1, 0.f) * fmaxf(yy2 - yy1, 0.f);
        float a2 = (b.z - b.x) * (b.w - b.y);
        if (inter / (a1 + a2 - inter + 1e-9f) > 0.6f) af_s[i] = 0;
      }
      __syncthreads();
    }
  } else if (c > NCAP) {
    while (kept < 100) {
      unsigned long long best = 0ull; int bi = 0;
      for (int i = t; i < c; i += 64) {
        unsigned long long k = bkey2[base + i];
        if (k > best) { best = k; bi = i; }
      }
#pragma unroll
      for (int o = 32; o; o >>= 1) {
        unsigned long long ok = __shfl_xor(best, o);
        int oi = __shfl_xor(bi, o);
        if (ok > best) { best = ok; bi = oi; }
      }
      if (best == 0ull) break;
      float4 wb = bbox2[base + bi];
      if (t == 0) { kbox[outB + kept] = wb; kkey[outB + kept] = best; }
      ++kept;
      float a1 = (wb.z - wb.x) * (wb.w - wb.y);
      for (int i = t; i < c; i += 64) {
        unsigned long long k = bkey2[base + i];
        if (!k) continue;
        float4 b = bbox2[base + i];
        float xx1 = fmaxf(wb.x, b.x), yy1 = fmaxf(wb.y, b.y);
        float xx2 = fminf(wb.z, b.z), yy2 = fminf(wb.w, b.w);
        float inter = fmaxf(xx2 - xx1, 0.f) * fmaxf(yy2 - yy1, 0.f);
        float a2 = (b.z - b.x) * (b.w - b.y);
        if (inter / (a1 + a2 - inter + 1e-9f) > 0.6f) bkey2[base + i] = 0ull;
      }
      __syncthreads();
    }
  }
  if (t == 0) kcnt[n * 80 + cls] = kept;
}

// ==================== NMS stage C: 80-way merge (keys preloaded to LDS) ====================
__global__ __launch_bounds__(64) void nms_merge_k(const float4* __restrict__ kbox,
                                                  const unsigned long long* __restrict__ kkey,
                                                  const int* __restrict__ kcnt,
                                                  float* __restrict__ outp)
{
  __shared__ unsigned long long lk[8000];
  __shared__ int head[80];
  __shared__ int cnts[80];
  const int n = blockIdx.x, t = threadIdx.x;
  for (int i = t; i < 80; i += 64) { head[i] = 0; cnts[i] = kcnt[n * 80 + i]; }
  for (int i = t; i < 8000; i += 64) lk[i] = kkey[n * 8000 + i];
  __syncthreads();
  for (int it = 0; it < 100; ++it) {
    unsigned long long best = 0ull; int bc = 0;
    for (int cls = t; cls < 80; cls += 64) {
      int h = head[cls];
      if (h < cnts[cls]) {
        unsigned long long k = lk[cls * 100 + h];
        if (k > best) { best = k; bc = cls; }
      }
    }
#pragma unroll
    for (int o = 32; o; o >>= 1) {
      unsigned long long ok = __shfl_xor(best, o);
      int oc = __shfl_xor(bc, o);
      if (ok > best) { best = ok; bc = oc; }
    }
    if (t == 0) {
      int basei = n * 100 + it;
      if (best != 0ull) {
        int idx = (n * 80 + bc) * 100 + head[bc];
        float4 b = kbox[idx];
        outp[basei * 4 + 0] = b.x; outp[basei * 4 + 1] = b.y;
        outp[basei * 4 + 2] = b.z; outp[basei * 4 + 3] = b.w;
        outp[1600 + basei] = __uint_as_float((unsigned)(best >> 24));
        outp[2000 + basei] = (float)bc;
        head[bc] = head[bc] + 1;
      } else {
        outp[basei * 4 + 0] = 0.f; outp[basei * 4 + 1] = 0.f;
        outp[basei * 4 + 2] = 0.f; outp[basei * 4 + 3] = 0.f;
        outp[1600 + basei] = 0.f;
        outp[2000 + basei] = -1.f;
      }
    }
    __syncthreads();
  }
}

// ==================== host ====================
extern "C" void kernel_launch(void* const* d_in, const int* in_sizes, int n_in,
                              void* d_out, int out_size, void* d_ws, size_t ws_size,
                              hipStream_t stream)
{
  (void)in_sizes; (void)n_in; (void)out_size; (void)ws_size;
  const float* p3 = (const float*)d_in[0];
  const float* p4 = (const float*)d_in[1];
  const float* p5 = (const float*)d_in[2];
  const float* p6 = (const float*)d_in[3];
  const float* p7 = (const float*)d_in[4];
  const float* cls_tw  = (const float*)d_in[5];
  const float* cls_tb  = (const float*)d_in[6];
  const float* bbox_tw = (const float*)d_in[7];
  const float* bbox_tb = (const float*)d_in[8];
  const float* wcls    = (const float*)d_in[9];
  const float* bcls    = (const float*)d_in[10];
  const float* wbox    = (const float*)d_in[11];
  const float* bbox_b  = (const float*)d_in[12];
  const float* wctr    = (const float*)d_in[13];
  const float* bctr    = (const float*)d_in[14];
  const float* scales  = (const float*)d_in[15];
  float* out = (float*)d_out;

  Geo G;
  const int Hs[5] = {100, 50, 25, 13, 7};
  {
    int tpre = 0, ppre = 0, bpre = 0, phw = 0, hw = 0;
    for (int l = 0; l < 5; ++l) {
      int H = Hs[l], W = Hs[l];
      G.Ha[l] = H; G.Wa[l] = W; G.PWa[l] = W + 2; G.PHWa[l] = (H + 2) * (W + 2);
      G.TXa[l] = (W + 15) / 16;
      int TY = (H + 3) / 4;
      G.tp[l] = tpre;  tpre += G.TXa[l] * TY;
      G.pb[l] = ppre;  ppre += (H * W + 63) / 64;
      G.bb[l] = bpre;  bpre += (H * W + 255) / 256;
      G.phwOff[l] = phw; phw += G.PHWa[l];
      G.hwOff[l]  = hw;  hw  += H * W;
    }
    G.tp[5] = tpre; G.pb[5] = ppre; G.bb[5] = bpre;
  }
  const int nTiles = G.tp[5];   // 247
  const int nPrep  = G.pb[5];   // 211
  const int nBoxB  = G.bb[5];   // 55
  const int sumHW = 13343;
  const size_t scoreBytes  = (size_t)sumHW * 4 * 80 * 4;
  const size_t deltasBytes = (size_t)sumHW * 4 * 4 * 4;

  char* ws = (char*)d_ws;
  size_t off = 0;
  auto alloc = [&](size_t bytes) -> void* {
    off = (off + 255) & ~(size_t)255;
    void* p = ws + off; off += bytes; return p;
  };
  const size_t bufBytes = 2ull * PLANE * 2;   // one fp16 split-plane act buffer = 57.9 MB

  short* wt     = (short*)alloc((size_t)8 * 2 * 589824 * 2);
  float* cbox   = (float*)alloc(4ull * 5000 * 4 * 4);
  float* csc    = (float*)alloc(4ull * 5000 * 4);
  float* ccls   = (float*)alloc(4ull * 5000 * 4);
  float* cgid   = (float*)alloc(4ull * 5000 * 4);
  unsigned* hist = (unsigned*)alloc(20ull * 2048 * 4);
  unsigned* thr  = (unsigned*)alloc(20ull * 8 * 4);
  float4* bbox2 = (float4*)alloc(4ull * 5000 * 16);
  unsigned long long* bkey2 = (unsigned long long*)alloc(4ull * 5000 * 8);
  int* coff     = (int*)alloc(4ull * 81 * 4);
  float4* kbox  = (float4*)alloc(320ull * 100 * 16);
  unsigned long long* kkey = (unsigned long long*)alloc(320ull * 100 * 8);
  int* kcnt     = (int*)alloc(320ull * 4);
  short* C = (short*)alloc(bufBytes);
  short* A = (short*)alloc(bufBytes);
  short* B = (short*)alloc(bufBytes);
  float* score  = (float*)alloc(scoreBytes);
  float* deltas = (float*)alloc(deltasBytes);

  hipMemsetAsync(csc,  0, 4ull * 5000 * 4, stream);
  hipMemsetAsync(ccls, 0, 4ull * 5000 * 4, stream);
  hipMemsetAsync(cgid, 0, 4ull * 5000 * 4, stream);
  hipMemsetAsync(thr,  0, 20ull * 8 * 4, stream);
  hipMemsetAsync(C, 0, bufBytes, stream);
  hipMemsetAsync(A, 0, bufBytes, stream);
  hipMemsetAsync(B, 0, bufBytes, stream);

  wtrans_k<<<1024, 256, 0, stream>>>(cls_tw, bbox_tw, wt);

  const size_t LSTRIDE = 2ull * 589824;  // shorts per conv layer (2 planes)
  dim3 cg(8 * nTiles);  // 1976 blocks, XCD-swizzled (stride nT, bijective)

  // prep once -> C; cls: C->A->B->A->B, head(B); bbox: C->A->C->A->C, head(C)
  prep_all_k<<<dim3(nPrep, 4), 256, 0, stream>>>(p3, p4, p5, p6, p7, C, G);
  conv_all_k<<<cg, 256, 0, stream>>>(C, wt + 0 * LSTRIDE, cls_tb + 0 * 256, A, G);
  conv_all_k<<<cg, 256, 0, stream>>>(A, wt + 1 * LSTRIDE, cls_tb + 1 * 256, B, G);
  conv_all_k<<<cg, 256, 0, stream>>>(B, wt + 2 * LSTRIDE, cls_tb + 2 * 256, A, G);
  conv_all_k<<<cg, 256, 0, stream>>>(A, wt + 3 * LSTRIDE, cls_tb + 3 * 256, B, G);
  cls_head_k<<<dim3(nPrep, 4), 256, 0, stream>>>(B, wcls, bcls, score, G);
  conv_all_k<<<cg, 256, 0, stream>>>(C, wt + 4 * LSTRIDE, bbox_tb + 0 * 256, A, G);
  conv_all_k<<<cg, 256, 0, stream>>>(A, wt + 5 * LSTRIDE, bbox_tb + 1 * 256, C, G);
  conv_all_k<<<cg, 256, 0, stream>>>(C, wt + 6 * LSTRIDE, bbox_tb + 2 * 256, A, G);
  conv_all_k<<<cg, 256, 0, stream>>>(A, wt + 7 * LSTRIDE, bbox_tb + 3 * 256, C, G);
  box_head_k<<<dim3(nBoxB, 4), 256, 0, stream>>>(C, wbox, bbox_b, wctr, bctr, scales,
                                                 score, deltas, G);

  // exact top-1000 per (level, image)
  const int hb = 196;
  for (int phase = 0; phase < 3; ++phase) {
    hipMemsetAsync(hist, 0, 20ull * 2048 * 4, stream);
    hist_k<<<dim3(hb, 20), 256, 0, stream>>>(score, thr, hist, phase, G);
    scan_k<<<20, 256, 0, stream>>>(hist, thr, phase);
  }
  select_k<<<dim3(hb, 20), 256, 0, stream>>>(score, deltas, thr, cbox, csc, ccls, cgid, G);

  // NMS: bucket -> per-class sorted-scan greedy (320 waves) -> 80-way merge
  nms_bucket_k<<<4, 256, 0, stream>>>(cbox, csc, ccls, cgid, bbox2, bkey2, coff);
  nms_class_k<<<dim3(80, 4), 64, 0, stream>>>(bbox2, bkey2, coff, kbox, kkey, kcnt);
  nms_merge_k<<<4, 64, 0, stream>>>(kbox, kkey, kcnt, out);
}

// Round 19
// 2150.278 us; speedup vs baseline: 1.0596x; 1.0557x over previous
//
#include <hip/hip_runtime.h>
#include <math.h>

typedef short s8v __attribute__((ext_vector_type(8)));
typedef short s4v __attribute__((ext_vector_type(4)));
typedef float f4v __attribute__((ext_vector_type(4)));
typedef _Float16 h8v __attribute__((ext_vector_type(8)));

__device__ __forceinline__ float sigf(float x) { return 1.f / (1.f + expf(-x)); }
__device__ __forceinline__ float f16f(short v) {
  return (float)__builtin_bit_cast(_Float16, v);
}

#define SCALE_CLAMP 4.135166556742356f
#define IMG_SIZE 800.f
#define PLANE 14482432ull   // shorts per activation plane: sumPHW(14143)*4*256
#define W_SCALE 1024.f
#define A_SCALE 64.f
#define ACC_RESCALE 1.52587890625e-5f   // 2^-16

// fp16 2-way split (round-to-nearest): x ~= h + l, residual <= 2^-24 |x|
__device__ __forceinline__ void split2(float x, short& h, short& l) {
  _Float16 hf = (_Float16)x;
  _Float16 lf = (_Float16)(x - (float)hf);
  h = __builtin_bit_cast(short, hf);
  l = __builtin_bit_cast(short, lf);
}

struct Geo {
  int tp[6];                 // conv tile prefix per level (4x16 tiles)
  int TXa[5];
  int Ha[5], Wa[5], PWa[5], PHWa[5];
  int phwOff[5];
  int hwOff[5];
  int pb[6];
  int bb[6];
};

// ==================== weight split+transpose (fp16 h/l, x1024) ====================
__global__ __launch_bounds__(256) void wtrans_k(const float* __restrict__ cls_tw,
                                                const float* __restrict__ bbox_tw,
                                                short* __restrict__ wt)
{
  const int total = 589824;
  for (int u = blockIdx.x * 256 + threadIdx.x; u < total; u += gridDim.x * 256) {
    int layer = u / 73728;
    int r = u - layer * 73728;
    int tap = r / 8192;  r -= tap * 8192;
    int cc  = r / 1024;  r -= cc * 1024;
    int qq  = r / 256;   int ko = r - qq * 256;
    int cibase = cc * 32 + qq * 8;
    const float* src = (layer < 4) ? (cls_tw + (size_t)layer * 589824)
                                   : (bbox_tw + (size_t)(layer - 4) * 589824);
    s8v hv, lv;
#pragma unroll
    for (int e = 0; e < 8; ++e) {
      float x = src[(size_t)ko * 2304 + (size_t)(cibase + e) * 9 + tap] * W_SCALE;
      short h, l; split2(x, h, l);
      hv[e] = h; lv[e] = l;
    }
    size_t dbase = (size_t)layer * 1179648 + (((size_t)tap * 8 + cc) * 4 + qq) * 2048 + (size_t)ko * 8;
    *(s8v*)(wt + dbase) = hv;
    *(s8v*)(wt + dbase + 589824) = lv;
  }
}

// ==================== NCHW fp32 -> padded split-plane fp16x2 (x64) ====================
__global__ __launch_bounds__(256) void prep_all_k(const float* __restrict__ p3, const float* __restrict__ p4,
                                                  const float* __restrict__ p5, const float* __restrict__ p6,
                                                  const float* __restrict__ p7,
                                                  short* __restrict__ out, Geo g)
{
  __shared__ float tl[64][260];
  int bx = blockIdx.x, t = threadIdx.x, n = blockIdx.y;
  int l = 0; while (l < 4 && bx >= g.pb[l + 1]) ++l;
  const float* in = (l == 0) ? p3 : (l == 1) ? p4 : (l == 2) ? p5 : (l == 3) ? p6 : p7;
  int H = g.Ha[l], W = g.Wa[l], PW = g.PWa[l], PHW = g.PHWa[l], HW = H * W;
  int P0 = (bx - g.pb[l]) * 64;
  const float* inN = in + (size_t)n * HW * 256;
  int sub = t >> 6, pl = t & 63;
  int pos = P0 + pl;
  for (int i = 0; i < 64; ++i) {
    int ci = i * 4 + sub;
    tl[pl][ci] = (pos < HW) ? inN[(size_t)ci * HW + pos] : 0.f;
  }
  __syncthreads();
  int pl2 = t >> 2, cq = (t & 3) * 64;
  int pos2 = P0 + pl2;
  if (pos2 < HW) {
    int y = pos2 / W, x = pos2 - y * W;
    size_t oo = ((size_t)g.phwOff[l] * 4 + (size_t)n * PHW + (size_t)(y + 1) * PW + (x + 1)) * 256 + cq;
#pragma unroll
    for (int grp = 0; grp < 8; ++grp) {
      s8v hv, lv;
#pragma unroll
      for (int e = 0; e < 8; ++e) {
        short h, lo; split2(tl[pl2][cq + grp * 8 + e] * A_SCALE, h, lo);
        hv[e] = h; lv[e] = lo;
      }
      *(s8v*)(out + oo + grp * 8) = hv;
      *(s8v*)(out + PLANE + oo + grp * 8) = lv;
    }
  }
}

// ==================== MFMA conv 3x3 + bias + relu (fp16 16x16x32, 3 products) ====================
// r13-measured-best configuration: QS=128 (no wrap; compile-time ds offsets),
// half-pipelined weight prefetch (wH0/wH1), launch_bounds(256,4), bijective
// stride-nT XCD swizzle. 2.165 ms total, conv 218us @ FETCH 62MB, MfmaUtil 47.5%.
#define QS    128
#define PSTR  4096   // shorts per plane (512*8)
#define BSTR  8192   // shorts per buffer (2 planes)
__global__ __launch_bounds__(256, 4) void conv_all_k(const short* __restrict__ in0,
                                                     const short* __restrict__ wtL,
                                                     const float* __restrict__ bias,
                                                     short* __restrict__ out0, Geo g)
{
  __shared__ short act_s[2 * BSTR];  // 32768 B

  const int t = threadIdx.x;
  const int lane = t & 63, wave = t >> 6;
  const int wcol = wave & 1, wko = wave >> 1;
  const int nT = g.tp[5];
  int bid = blockIdx.x;
  int wgid = (bid & 7) * nT + (bid >> 3);   // bijective on [0, 8*nT)
  const int n = wgid / (2 * nT);            // image 0..3
  int r2 = wgid - n * (2 * nT);
  int bx = r2 >> 1;
  const int ko0 = (r2 & 1) * 128;
  int l = 0; while (l < 4 && bx >= g.tp[l + 1]) ++l;
  const int H = g.Ha[l], W = g.Wa[l], PW = g.PWa[l], PHW = g.PHWa[l];
  const int lt = bx - g.tp[l];
  const int TX = g.TXa[l];
  const int ty = lt / TX, tx = lt - ty * TX;
  const int R0 = ty * 4, C0 = tx * 16;
  const size_t bi = ((size_t)g.phwOff[l] * 4 + (size_t)n * PHW) * 256;
  const short* inN = in0 + bi;
  short* outN = out0 + bi;

  const int r = lane & 15, q = lane >> 4;
  const int cb = wcol * 8;
  const short* wlane = wtL + (size_t)q * 2048 + (size_t)(ko0 + wko * 64 + r) * 8;
  // per-thread LDS read base (slot units); mi/dy/dx add compile-time immediates
  const int abase = q * QS + 2 * q + (r >> 3) * 18 + cb + (r & 7);

  int soff[2];
#pragma unroll
  for (int k = 0; k < 2; ++k) {
    int j = t + k * 256;                 // 0..511
    int qq = j >> 7, ppos = j & 127;
    int lpos = ppos - 2 * qq;
    if (lpos < 0) lpos = 0;
    if (lpos > 107) lpos = 107;          // dead slots (never read) -> clamp
    int row = lpos / 18, col = lpos - row * 18;
    int prow = R0 + row; if (prow > H + 1) prow = H + 1;
    int pcol = C0 + col; if (pcol > W + 1) pcol = W + 1;
    soff[k] = (prow * PW + pcol) * 256 + qq * 8;
  }

  f4v acc[2][4];
#pragma unroll
  for (int mi = 0; mi < 2; ++mi)
#pragma unroll
    for (int ni = 0; ni < 4; ++ni) { f4v z = {0.f, 0.f, 0.f, 0.f}; acc[mi][ni] = z; }

  auto stage = [&](int cc, int buf) {
#pragma unroll
    for (int k = 0; k < 2; ++k)
#pragma unroll
      for (int p = 0; p < 2; ++p) {
        const short* src = inN + (size_t)p * PLANE + (size_t)(soff[k] + cc * 32);
        short* dst = &act_s[(size_t)buf * BSTR + (size_t)p * PSTR + (size_t)(t + k * 256) * 8];
#if __has_builtin(__builtin_amdgcn_global_load_lds)
        __builtin_amdgcn_global_load_lds((const __attribute__((address_space(1))) void*)src,
                                         (__attribute__((address_space(3))) void*)dst, 16, 0, 0);
#else
        *(s8v*)dst = *(const s8v*)src;
#endif
      }
  };

  auto loadW = [&](s8v (&w)[2][2], int cc2, int tap2, int half) {
    const short* base = wlane + (size_t)(tap2 * 8 + cc2) * 8192 + half * 256;
#pragma unroll
    for (int p = 0; p < 2; ++p)
#pragma unroll
      for (int k = 0; k < 2; ++k)
        w[p][k] = *(const s8v*)(base + (size_t)p * 589824 + k * 128);
  };

  // all offsets relative to (sbase + abase) are compile-time constants
  auto loadA = [&](s8v (&af)[2][2], int dy, int dx, int buf) {
    const int b0 = buf * BSTR + abase * 8;
    const int d = (dy * 18 + dx) * 8;
#pragma unroll
    for (int mi = 0; mi < 2; ++mi) {
      af[0][mi] = *(const s8v*)&act_s[b0 + mi * 288 + d];
      af[1][mi] = *(const s8v*)&act_s[b0 + PSTR + mi * 288 + d];
    }
  };

  auto runHalf = [&](const s8v (&w)[2][2], const s8v (&af)[2][2], int half) {
    const int PA[3] = {0, 0, 1};
    const int PB[3] = {0, 1, 0};
    __builtin_amdgcn_s_setprio(1);
#pragma unroll
    for (int pp = 0; pp < 3; ++pp)
#pragma unroll
      for (int mi = 0; mi < 2; ++mi)
#pragma unroll
        for (int k = 0; k < 2; ++k)
          acc[mi][half * 2 + k] = __builtin_amdgcn_mfma_f32_16x16x32_f16(
              __builtin_bit_cast(h8v, af[PA[pp]][mi]),
              __builtin_bit_cast(h8v, w[PB[pp]][k]),
              acc[mi][half * 2 + k], 0, 0, 0);
    __builtin_amdgcn_s_setprio(0);
  };

  s8v wH0[2][2], wH1[2][2], afr[2][2];
  stage(0, 0);
  loadW(wH0, 0, 0, 0);
  __syncthreads();

  int cur = 0;
  for (int cc = 0; cc < 8; ++cc) {
    if (cc < 7) stage(cc + 1, cur ^ 1);
#pragma unroll
    for (int tap = 0; tap < 9; ++tap) {
      const int dy = tap / 3, dx = tap - dy * 3;
      loadW(wH1, cc, tap, 1);
      loadA(afr, dy, dx, cur);
      runHalf(wH0, afr, 0);
      int ntap = tap + 1, ncc = cc;
      if (ntap == 9) { ntap = 0; ++ncc; }
      if (ncc < 8) loadW(wH0, ncc, ntap, 0);
      runHalf(wH1, afr, 1);
    }
    __syncthreads();
    cur ^= 1;
  }

#pragma unroll
  for (int mi = 0; mi < 2; ++mi) {
#pragma unroll
    for (int ni = 0; ni < 4; ++ni) {
      int ko = ko0 + wko * 64 + ni * 16 + r;
      float bv = bias[ko];
#pragma unroll
      for (int reg = 0; reg < 4; ++reg) {
        int rm = q * 4 + reg;
        int orow = R0 + 2 * mi + (rm >> 3);
        int ocol = C0 + cb + (rm & 7);
        if (orow < H && ocol < W) {
          float real = acc[mi][ni][reg] * ACC_RESCALE + bv;
          float vv = fmaxf(real, 0.f) * A_SCALE;
          short h, lo; split2(vv, h, lo);
          size_t oo = ((size_t)(orow + 1) * PW + (ocol + 1)) * 256 + ko;
          outN[oo] = h; outN[PLANE + oo] = lo;
        }
      }
    }
  }
}

// ==================== cls head (all levels): 1x1x80 + sigmoid ====================
__global__ __launch_bounds__(256) void cls_head_k(const short* __restrict__ act,
                                                  const float* __restrict__ wcls,
                                                  const float* __restrict__ bcls,
                                                  float* __restrict__ score, Geo g)
{
  __shared__ int   p2s[64];
  __shared__ float as_[64][69];
  __shared__ float ws_[64][84];
  const int t = threadIdx.x;
  const int n = blockIdx.y;
  int bx = blockIdx.x;
  int l = 0; while (l < 4 && bx >= g.pb[l + 1]) ++l;
  const int H = g.Ha[l], W = g.Wa[l], PW = g.PWa[l], PHW = g.PHWa[l], HW = H * W;
  const int P0 = (bx - g.pb[l]) * 64;
  if (t < 64) {
    int p = P0 + t; if (p >= HW) p = HW - 1;
    int y = p / W, x = p - y * W;
    p2s[t] = (y + 1) * PW + x + 1;
  }
  __syncthreads();
  float accv[4][5];
#pragma unroll
  for (int i = 0; i < 4; ++i)
#pragma unroll
    for (int j = 0; j < 5; ++j) accv[i][j] = 0.f;

  const short* actN = act + ((size_t)g.phwOff[l] * 4 + (size_t)n * PHW) * 256;
  const int pg = t >> 4, cg = t & 15;
  const float inv = 1.f / A_SCALE;

  for (int c0 = 0; c0 < 256; c0 += 64) {
    for (int i = t; i < 1024; i += 256) {
      int pos = i >> 4, c4 = i & 15;
      size_t o = (size_t)p2s[pos] * 256 + c0 + c4 * 4;
      s4v hv = *(const s4v*)(actN + o);
      s4v lv = *(const s4v*)(actN + PLANE + o);
      float* dst = &as_[pos][c4 * 4];
#pragma unroll
      for (int e = 0; e < 4; ++e) dst[e] = (f16f(hv[e]) + f16f(lv[e])) * inv;
    }
    for (int i = t; i < 1280; i += 256) {
      int c = i >> 4, c4 = i & 15;
      float4 v = *(const float4*)(wcls + (size_t)c * 256 + c0 + c4 * 4);
      ws_[c4 * 4 + 0][c] = v.x; ws_[c4 * 4 + 1][c] = v.y;
      ws_[c4 * 4 + 2][c] = v.z; ws_[c4 * 4 + 3][c] = v.w;
    }
    __syncthreads();
#pragma unroll 8
    for (int ci = 0; ci < 64; ++ci) {
#pragma unroll
      for (int i = 0; i < 4; ++i) {
        float a = as_[pg * 4 + i][ci];
#pragma unroll
        for (int j = 0; j < 5; ++j)
          accv[i][j] = fmaf(a, ws_[ci][cg * 5 + j], accv[i][j]);
      }
    }
    __syncthreads();
  }
  float* sB = score + ((size_t)g.hwOff[l] * 4 + (size_t)n * HW) * 80;
#pragma unroll
  for (int i = 0; i < 4; ++i) {
    int p = P0 + pg * 4 + i;
    if (p >= HW) continue;
#pragma unroll
    for (int j = 0; j < 5; ++j) {
      int c = cg * 5 + j;
      sB[(size_t)p * 80 + c] = sigf(accv[i][j] + bcls[c]);
    }
  }
}

// ==================== box head (all levels) ====================
__global__ __launch_bounds__(256) void box_head_k(const short* __restrict__ act,
                                                  const float* __restrict__ wbox,
                                                  const float* __restrict__ bb,
                                                  const float* __restrict__ wctr,
                                                  const float* __restrict__ bc,
                                                  const float* __restrict__ scales,
                                                  float* __restrict__ score,
                                                  float* __restrict__ deltas, Geo g)
{
  int n = blockIdx.y;
  int bx = blockIdx.x;
  int l = 0; while (l < 4 && bx >= g.bb[l + 1]) ++l;
  const int H = g.Ha[l], W = g.Wa[l], PW = g.PWa[l], PHW = g.PHWa[l], HW = H * W;
  int p = (bx - g.bb[l]) * 256 + threadIdx.x;
  if (p >= HW) return;
  int y = p / W, x = p - y * W;
  const short* a = act + ((size_t)g.phwOff[l] * 4 + (size_t)n * PHW + (size_t)(y + 1) * PW + x + 1) * 256;
  const float inv = 1.f / A_SCALE;
  float d0 = 0, d1 = 0, d2 = 0, d3 = 0, ct = 0;
  for (int gI = 0; gI < 32; ++gI) {
    s8v hv = *(const s8v*)(a + gI * 8);
    s8v lv = *(const s8v*)(a + PLANE + gI * 8);
#pragma unroll
    for (int e = 0; e < 8; ++e) {
      float av = (f16f(hv[e]) + f16f(lv[e])) * inv;
      int c = gI * 8 + e;
      d0 = fmaf(av, wbox[c], d0);
      d1 = fmaf(av, wbox[256 + c], d1);
      d2 = fmaf(av, wbox[512 + c], d2);
      d3 = fmaf(av, wbox[768 + c], d3);
      ct = fmaf(av, wctr[c], ct);
    }
  }
  float sl = scales[l];
  float* dd = deltas + ((size_t)g.hwOff[l] * 4 + (size_t)n * HW + p) * 4;
  dd[0] = sl * (d0 + bb[0]); dd[1] = sl * (d1 + bb[1]);
  dd[2] = sl * (d2 + bb[2]); dd[3] = sl * (d3 + bb[3]);
  float sct = sigf(ct + bc[0]);
  float* sp = score + ((size_t)g.hwOff[l] * 4 + (size_t)n * HW + p) * 80;
#pragma unroll
  for (int i = 0; i < 20; ++i) {
    float4 v = ((float4*)sp)[i];
    v.x *= sct; v.y *= sct; v.z *= sct; v.w *= sct;
    v.x = (v.x > 0.05f) ? v.x : 0.f;
    v.y = (v.y > 0.05f) ? v.y : 0.f;
    v.z = (v.z > 0.05f) ? v.z : 0.f;
    v.w = (v.w > 0.05f) ? v.w : 0.f;
    ((float4*)sp)[i] = v;
  }
}

// ==================== exact top-1000: 3-pass bit histogram, 20 groups ====================
__global__ __launch_bounds__(256) void hist_k(const float* __restrict__ score,
                                              const unsigned* __restrict__ thr,
                                              unsigned* __restrict__ hist, int phase, Geo g)
{
  const int grp = blockIdx.y;
  const int l = grp >> 2, n = grp & 3;
  const int HW = g.Ha[l] * g.Wa[l];
  const int M = HW * 80;
  const float* s = score + ((size_t)g.hwOff[l] * 4 + (size_t)n * HW) * 80;
  unsigned* h = hist + grp * 2048;
  const unsigned* tr = thr + grp * 8;
  __shared__ unsigned lh[2048];
  for (int i = threadIdx.x; i < 2048; i += 256) lh[i] = 0u;
  __syncthreads();
  unsigned B1 = 0, pref = 0;
  if (phase == 1) B1 = tr[0];
  if (phase == 2) pref = (tr[0] << 11) | tr[1];
  for (int idx = blockIdx.x * 256 + threadIdx.x; idx < M; idx += gridDim.x * 256) {
    float v = s[idx];
    if (v > 0.f) {
      unsigned b = __float_as_uint(v);
      if (phase == 0) atomicAdd(&lh[b >> 20], 1u);
      else if (phase == 1) { if ((b >> 20) == B1) atomicAdd(&lh[(b >> 9) & 0x7FFu], 1u); }
      else { if ((b >> 9) == pref) atomicAdd(&lh[b & 0x1FFu], 1u); }
    }
  }
  __syncthreads();
  for (int i = threadIdx.x; i < 2048; i += 256) { unsigned v = lh[i]; if (v) atomicAdd(&h[i], v); }
}

__global__ __launch_bounds__(256) void scan_k(unsigned* __restrict__ hist,
                                              unsigned* __restrict__ thr, int phase)
{
  const int grp = blockIdx.x, t = threadIdx.x;
  unsigned* h  = hist + grp * 2048;
  unsigned* tr = thr + grp * 8;
  const int nb = (phase == 2) ? 512 : 2048;
  const int PB = nb / 256;
  unsigned target = 1000u;
  bool dead = false;
  if (phase >= 1) {
    target = 1000u - tr[2];
    if (tr[0] == 0xFFFFFFFFu) dead = true;
    if (phase == 2 && tr[1] == 0xFFFFFFFFu) dead = true;
  }
  __shared__ unsigned ps[256];
  __shared__ unsigned s_tot;
  const int hi = nb - t * PB;
  unsigned lsum = 0;
  for (int k = 0; k < PB; ++k) lsum += h[hi - 1 - k];
  ps[t] = lsum;
  __syncthreads();
  if (t == 0) {
    unsigned cum = 0;
    for (int i = 0; i < 256; ++i) { unsigned tmp = ps[i]; ps[i] = cum; cum += tmp; }
    s_tot = cum;
  }
  __syncthreads();
  unsigned exc = ps[t], tot = s_tot;
  if (!dead && tot >= target) {
    if (exc < target && exc + lsum >= target) {
      unsigned cum = exc; int bf = 0; unsigned above = 0;
      for (int k = 0; k < PB; ++k) {
        int bidx = hi - 1 - k;
        unsigned c = h[bidx];
        if (cum < target && cum + c >= target) { bf = bidx; above = cum; }
        cum += c;
      }
      if (phase == 0)      { tr[0] = (unsigned)bf; tr[2] = above; }
      else if (phase == 1) { tr[1] = (unsigned)bf; tr[2] = tr[2] + above; }
      else {
        unsigned T = (tr[0] << 20) | (tr[1] << 9) | (unsigned)bf;
        tr[3] = T; tr[4] = target - above;
      }
    }
  } else if (t == 0) {
    if (phase == 0)      { tr[0] = 0xFFFFFFFFu; tr[2] = 0u; }
    else if (phase == 1) { tr[1] = 0xFFFFFFFFu; }
    else                 { tr[3] = 0u; tr[4] = 0u; }
  }
  if (phase == 2 && t == 0) { tr[5] = 0u; tr[6] = 0u; }
}

// ==================== select + decode ====================
__global__ __launch_bounds__(256) void select_k(const float* __restrict__ score,
                                                const float* __restrict__ deltas,
                                                unsigned* __restrict__ thr,
                                                float* __restrict__ cbox, float* __restrict__ csc,
                                                float* __restrict__ ccls, float* __restrict__ cgid,
                                                Geo g)
{
  const int grp = blockIdx.y;
  const int l = grp >> 2, n = grp & 3;
  const int W = g.Wa[l];
  const int HW = g.Ha[l] * W;
  const int M = HW * 80;
  const float stride_ = (float)(8 << l);
  const float* s = score + ((size_t)g.hwOff[l] * 4 + (size_t)n * HW) * 80;
  const float* dBase = deltas + ((size_t)g.hwOff[l] * 4 + (size_t)n * HW) * 4;
  unsigned* tr = thr + grp * 8;
  const unsigned T = tr[3], need = tr[4];
  for (int idx = blockIdx.x * 256 + threadIdx.x; idx < M; idx += gridDim.x * 256) {
    float v = s[idx];
    if (!(v > 0.f)) continue;
    unsigned b = __float_as_uint(v);
    int slot = -1;
    if (b > T) slot = (int)atomicAdd(&tr[5], 1u);
    else if (b == T) {
      unsigned e = atomicAdd(&tr[6], 1u);
      if (e < need) slot = (int)(1000u - need + e);
    }
    if (slot < 0) continue;
    int p = idx / 80, c = idx - p * 80;
    int y = p / W, x = p - y * W;
    const float* d = dBase + (size_t)p * 4;
    float sz  = 8.f * stride_;
    float acx = ((float)x + 0.5f) * stride_;
    float acy = ((float)y + 0.5f) * stride_;
    float dx = d[0] / 10.f, dy = d[1] / 10.f;
    float dw = fminf(d[2] / 5.f, SCALE_CLAMP);
    float dh = fminf(d[3] / 5.f, SCALE_CLAMP);
    float pcx = dx * sz + acx;
    float pcy = dy * sz + acy;
    float pw = expf(dw) * sz;
    float ph = expf(dh) * sz;
    float x1 = pcx - 0.5f * pw, y1_ = pcy - 0.5f * ph;
    float x2 = pcx + 0.5f * pw, y2_ = pcy + 0.5f * ph;
    x1  = fminf(fmaxf(x1, 0.f),  IMG_SIZE);
    y1_ = fminf(fmaxf(y1_, 0.f), IMG_SIZE);
    x2  = fminf(fmaxf(x2, 0.f),  IMG_SIZE);
    y2_ = fminf(fmaxf(y2_, 0.f), IMG_SIZE);
    int cslot = n * 5000 + l * 1000 + slot;
    ((float4*)cbox)[cslot] = make_float4(x1, y1_, x2, y2_);
    csc[cslot]  = sqrtf(v);
    ccls[cslot] = (float)c;
    cgid[cslot] = (float)(((unsigned)l << 20) | (unsigned)idx);
  }
}

// ==================== NMS stage A: bucket candidates by class (1 block/image) ====================
__global__ __launch_bounds__(256) void nms_bucket_k(const float* __restrict__ cbox,
                                                    const float* __restrict__ csc,
                                                    const float* __restrict__ ccls,
                                                    const float* __restrict__ cgid,
                                                    float4* __restrict__ bbox2,
                                                    unsigned long long* __restrict__ bkey2,
                                                    int* __restrict__ coff)
{
  __shared__ unsigned cnt[80];
  __shared__ unsigned off_s[81];
  const int n = blockIdx.x, t = threadIdx.x;
  for (int i = t; i < 80; i += 256) cnt[i] = 0u;
  __syncthreads();
  for (int i = t; i < 5000; i += 256) {
    float s = csc[n * 5000 + i];
    if (s > 0.f) atomicAdd(&cnt[(int)ccls[n * 5000 + i]], 1u);
  }
  __syncthreads();
  if (t == 0) {
    unsigned c = 0;
    for (int k = 0; k < 80; ++k) { off_s[k] = c; c += cnt[k]; }
    off_s[80] = c;
  }
  __syncthreads();
  for (int i = t; i < 81; i += 256) coff[n * 81 + i] = (int)off_s[i];
  for (int i = t; i < 80; i += 256) cnt[i] = 0u;
  __syncthreads();
  for (int i = t; i < 5000; i += 256) {
    float s = csc[n * 5000 + i];
    if (s > 0.f) {
      int c = (int)ccls[n * 5000 + i];
      unsigned p = atomicAdd(&cnt[c], 1u);
      int dst = n * 5000 + (int)off_s[c] + (int)p;
      bbox2[dst] = ((const float4*)cbox)[n * 5000 + i];
      unsigned long long sb = (unsigned long long)__float_as_uint(s);
      unsigned gid = (unsigned)cgid[n * 5000 + i];
      bkey2[dst] = (sb << 24) | (unsigned long long)(0xFFFFFFu - gid);
    }
  }
}

// ==================== NMS stage B: per-(image,class) sorted-scan greedy, one wave ====================
#define NCAP 1536
__global__ __launch_bounds__(64) void nms_class_k(const float4* __restrict__ bbox2,
                                                  unsigned long long* __restrict__ bkey2,
                                                  const int* __restrict__ coff,
                                                  float4* __restrict__ kbox,
                                                  unsigned long long* __restrict__ kkey,
                                                  int* __restrict__ kcnt)
{
  __shared__ unsigned long long key_s[NCAP];
  __shared__ unsigned long long sk_s[NCAP];
  __shared__ float4 sb_s[NCAP];
  __shared__ unsigned char af_s[NCAP + 64];
  const int cls = blockIdx.x, n = blockIdx.y, t = threadIdx.x;
  const int lo = coff[n * 81 + cls], hi = coff[n * 81 + cls + 1];
  const int c = hi - lo;
  const int base = n * 5000 + lo;
  const int outB = (n * 80 + cls) * 100;
  int kept = 0;
  if (c > 0 && c <= NCAP) {
    const int nch = (c + 63) >> 6;
    for (int i = t; i < nch * 64; i += 64) af_s[i] = 0;
    for (int i = t; i < c; i += 64) key_s[i] = bkey2[base + i];
    __syncthreads();
    for (int i = t; i < c; i += 64) {
      unsigned long long ki = key_s[i];
      int rk = 0;
      for (int m = 0; m < c; ++m) rk += (key_s[m] > ki) ? 1 : 0;
      sk_s[rk] = ki;
      sb_s[rk] = bbox2[base + i];
      af_s[rk] = 1;
    }
    __syncthreads();
    int p = -1;
    while (kept < 100) {
      int np = -1;
      int j0 = (p + 1) >> 6;
      for (int j = j0; j < nch; ++j) {
        int pos = j * 64 + t;
        unsigned long long w = __ballot(af_s[pos] != 0);
        if (j == j0) { int sh = (p + 1) & 63; if (sh) w &= (~0ull) << sh; }
        if (w) { np = j * 64 + (int)__builtin_ctzll(w); break; }
      }
      if (np < 0) break;
      p = np;
      float4 wb = sb_s[p];
      if (t == 0) { kbox[outB + kept] = wb; kkey[outB + kept] = sk_s[p]; }
      ++kept;
      float a1 = (wb.z - wb.x) * (wb.w - wb.y);
      for (int i = p + t; i < c; i += 64) {
        if (!af_s[i]) continue;
        float4 b = sb_s[i];
        float xx1 = fmaxf(wb.x, b.x), yy1 = fmaxf(wb.y, b.y);
        float xx2 = fminf(wb.z, b.z), yy2 = fminf(wb.w, b.w);
        float inter = fmaxf(xx2 - xx1, 0.f) * fmaxf(yy2 - yy1, 0.f);
        float a2 = (b.z - b.x) * (b.w - b.y);
        if (inter / (a1 + a2 - inter + 1e-9f) > 0.6f) af_s[i] = 0;
      }
      __syncthreads();
    }
  } else if (c > NCAP) {
    while (kept < 100) {
      unsigned long long best = 0ull; int bi = 0;
      for (int i = t; i < c; i += 64) {
        unsigned long long k = bkey2[base + i];
        if (k > best) { best = k; bi = i; }
      }
#pragma unroll
      for (int o = 32; o; o >>= 1) {
        unsigned long long ok = __shfl_xor(best, o);
        int oi = __shfl_xor(bi, o);
        if (ok > best) { best = ok; bi = oi; }
      }
      if (best == 0ull) break;
      float4 wb = bbox2[base + bi];
      if (t == 0) { kbox[outB + kept] = wb; kkey[outB + kept] = best; }
      ++kept;
      float a1 = (wb.z - wb.x) * (wb.w - wb.y);
      for (int i = t; i < c; i += 64) {
        unsigned long long k = bkey2[base + i];
        if (!k) continue;
        float4 b = bbox2[base + i];
        float xx1 = fmaxf(wb.x, b.x), yy1 = fmaxf(wb.y, b.y);
        float xx2 = fminf(wb.z, b.z), yy2 = fminf(wb.w, b.w);
        float inter = fmaxf(xx2 - xx1, 0.f) * fmaxf(yy2 - yy1, 0.f);
        float a2 = (b.z - b.x) * (b.w - b.y);
        if (inter / (a1 + a2 - inter + 1e-9f) > 0.6f) bkey2[base + i] = 0ull;
      }
      __syncthreads();
    }
  }
  if (t == 0) kcnt[n * 80 + cls] = kept;
}

// ==================== NMS stage C: 80-way merge (keys preloaded to LDS) ====================
__global__ __launch_bounds__(64) void nms_merge_k(const float4* __restrict__ kbox,
                                                  const unsigned long long* __restrict__ kkey,
                                                  const int* __restrict__ kcnt,
                                                  float* __restrict__ outp)
{
  __shared__ unsigned long long lk[8000];
  __shared__ int head[80];
  __shared__ int cnts[80];
  const int n = blockIdx.x, t = threadIdx.x;
  for (int i = t; i < 80; i += 64) { head[i] = 0; cnts[i] = kcnt[n * 80 + i]; }
  for (int i = t; i < 8000; i += 64) lk[i] = kkey[n * 8000 + i];
  __syncthreads();
  for (int it = 0; it < 100; ++it) {
    unsigned long long best = 0ull; int bc = 0;
    for (int cls = t; cls < 80; cls += 64) {
      int h = head[cls];
      if (h < cnts[cls]) {
        unsigned long long k = lk[cls * 100 + h];
        if (k > best) { best = k; bc = cls; }
      }
    }
#pragma unroll
    for (int o = 32; o; o >>= 1) {
      unsigned long long ok = __shfl_xor(best, o);
      int oc = __shfl_xor(bc, o);
      if (ok > best) { best = ok; bc = oc; }
    }
    if (t == 0) {
      int basei = n * 100 + it;
      if (best != 0ull) {
        int idx = (n * 80 + bc) * 100 + head[bc];
        float4 b = kbox[idx];
        outp[basei * 4 + 0] = b.x; outp[basei * 4 + 1] = b.y;
        outp[basei * 4 + 2] = b.z; outp[basei * 4 + 3] = b.w;
        outp[1600 + basei] = __uint_as_float((unsigned)(best >> 24));
        outp[2000 + basei] = (float)bc;
        head[bc] = head[bc] + 1;
      } else {
        outp[basei * 4 + 0] = 0.f; outp[basei * 4 + 1] = 0.f;
        outp[basei * 4 + 2] = 0.f; outp[basei * 4 + 3] = 0.f;
        outp[1600 + basei] = 0.f;
        outp[2000 + basei] = -1.f;
      }
    }
    __syncthreads();
  }
}

// ==================== host ====================
extern "C" void kernel_launch(void* const* d_in, const int* in_sizes, int n_in,
                              void* d_out, int out_size, void* d_ws, size_t ws_size,
                              hipStream_t stream)
{
  (void)in_sizes; (void)n_in; (void)out_size; (void)ws_size;
  const float* p3 = (const float*)d_in[0];
  const float* p4 = (const float*)d_in[1];
  const float* p5 = (const float*)d_in[2];
  const float* p6 = (const float*)d_in[3];
  const float* p7 = (const float*)d_in[4];
  const float* cls_tw  = (const float*)d_in[5];
  const float* cls_tb  = (const float*)d_in[6];
  const float* bbox_tw = (const float*)d_in[7];
  const float* bbox_tb = (const float*)d_in[8];
  const float* wcls    = (const float*)d_in[9];
  const float* bcls    = (const float*)d_in[10];
  const float* wbox    = (const float*)d_in[11];
  const float* bbox_b  = (const float*)d_in[12];
  const float* wctr    = (const float*)d_in[13];
  const float* bctr    = (const float*)d_in[14];
  const float* scales  = (const float*)d_in[15];
  float* out = (float*)d_out;

  Geo G;
  const int Hs[5] = {100, 50, 25, 13, 7};
  {
    int tpre = 0, ppre = 0, bpre = 0, phw = 0, hw = 0;
    for (int l = 0; l < 5; ++l) {
      int H = Hs[l], W = Hs[l];
      G.Ha[l] = H; G.Wa[l] = W; G.PWa[l] = W + 2; G.PHWa[l] = (H + 2) * (W + 2);
      G.TXa[l] = (W + 15) / 16;
      int TY = (H + 3) / 4;
      G.tp[l] = tpre;  tpre += G.TXa[l] * TY;
      G.pb[l] = ppre;  ppre += (H * W + 63) / 64;
      G.bb[l] = bpre;  bpre += (H * W + 255) / 256;
      G.phwOff[l] = phw; phw += G.PHWa[l];
      G.hwOff[l]  = hw;  hw  += H * W;
    }
    G.tp[5] = tpre; G.pb[5] = ppre; G.bb[5] = bpre;
  }
  const int nTiles = G.tp[5];   // 247
  const int nPrep  = G.pb[5];   // 211
  const int nBoxB  = G.bb[5];   // 55
  const int sumHW = 13343;
  const size_t scoreBytes  = (size_t)sumHW * 4 * 80 * 4;
  const size_t deltasBytes = (size_t)sumHW * 4 * 4 * 4;

  char* ws = (char*)d_ws;
  size_t off = 0;
  auto alloc = [&](size_t bytes) -> void* {
    off = (off + 255) & ~(size_t)255;
    void* p = ws + off; off += bytes; return p;
  };
  const size_t bufBytes = 2ull * PLANE * 2;   // one fp16 split-plane act buffer = 57.9 MB

  short* wt     = (short*)alloc((size_t)8 * 2 * 589824 * 2);
  float* cbox   = (float*)alloc(4ull * 5000 * 4 * 4);
  float* csc    = (float*)alloc(4ull * 5000 * 4);
  float* ccls   = (float*)alloc(4ull * 5000 * 4);
  float* cgid   = (float*)alloc(4ull * 5000 * 4);
  unsigned* hist = (unsigned*)alloc(20ull * 2048 * 4);
  unsigned* thr  = (unsigned*)alloc(20ull * 8 * 4);
  float4* bbox2 = (float4*)alloc(4ull * 5000 * 16);
  unsigned long long* bkey2 = (unsigned long long*)alloc(4ull * 5000 * 8);
  int* coff     = (int*)alloc(4ull * 81 * 4);
  float4* kbox  = (float4*)alloc(320ull * 100 * 16);
  unsigned long long* kkey = (unsigned long long*)alloc(320ull * 100 * 8);
  int* kcnt     = (int*)alloc(320ull * 4);
  short* C = (short*)alloc(bufBytes);
  short* A = (short*)alloc(bufBytes);
  short* B = (short*)alloc(bufBytes);
  float* score  = (float*)alloc(scoreBytes);
  float* deltas = (float*)alloc(deltasBytes);

  hipMemsetAsync(csc,  0, 4ull * 5000 * 4, stream);
  hipMemsetAsync(ccls, 0, 4ull * 5000 * 4, stream);
  hipMemsetAsync(cgid, 0, 4ull * 5000 * 4, stream);
  hipMemsetAsync(thr,  0, 20ull * 8 * 4, stream);
  hipMemsetAsync(C, 0, bufBytes, stream);
  hipMemsetAsync(A, 0, bufBytes, stream);
  hipMemsetAsync(B, 0, bufBytes, stream);

  wtrans_k<<<1024, 256, 0, stream>>>(cls_tw, bbox_tw, wt);

  const size_t LSTRIDE = 2ull * 589824;  // shorts per conv layer (2 planes)
  dim3 cg(8 * nTiles);  // 1976 blocks, XCD-swizzled (stride nT, bijective)

  // prep once -> C; cls: C->A->B->A->B, head(B); bbox: C->A->C->A->C, head(C)
  prep_all_k<<<dim3(nPrep, 4), 256, 0, stream>>>(p3, p4, p5, p6, p7, C, G);
  conv_all_k<<<cg, 256, 0, stream>>>(C, wt + 0 * LSTRIDE, cls_tb + 0 * 256, A, G);
  conv_all_k<<<cg, 256, 0, stream>>>(A, wt + 1 * LSTRIDE, cls_tb + 1 * 256, B, G);
  conv_all_k<<<cg, 256, 0, stream>>>(B, wt + 2 * LSTRIDE, cls_tb + 2 * 256, A, G);
  conv_all_k<<<cg, 256, 0, stream>>>(A, wt + 3 * LSTRIDE, cls_tb + 3 * 256, B, G);
  cls_head_k<<<dim3(nPrep, 4), 256, 0, stream>>>(B, wcls, bcls, score, G);
  conv_all_k<<<cg, 256, 0, stream>>>(C, wt + 4 * LSTRIDE, bbox_tb + 0 * 256, A, G);
  conv_all_k<<<cg, 256, 0, stream>>>(A, wt + 5 * LSTRIDE, bbox_tb + 1 * 256, C, G);
  conv_all_k<<<cg, 256, 0, stream>>>(C, wt + 6 * LSTRIDE, bbox_tb + 2 * 256, A, G);
  conv_all_k<<<cg, 256, 0, stream>>>(A, wt + 7 * LSTRIDE, bbox_tb + 3 * 256, C, G);
  box_head_k<<<dim3(nBoxB, 4), 256, 0, stream>>>(C, wbox, bbox_b, wctr, bctr, scales,
                                                 score, deltas, G);

  // exact top-1000 per (level, image)
  const int hb = 196;
  for (int phase = 0; phase < 3; ++phase) {
    hipMemsetAsync(hist, 0, 20ull * 2048 * 4, stream);
    hist_k<<<dim3(hb, 20), 256, 0, stream>>>(score, thr, hist, phase, G);
    scan_k<<<20, 256, 0, stream>>>(hist, thr, phase);
  }
  select_k<<<dim3(hb, 20), 256, 0, stream>>>(score, deltas, thr, cbox, csc, ccls, cgid, G);

  // NMS: bucket -> per-class sorted-scan greedy (320 waves) -> 80-way merge
  nms_bucket_k<<<4, 256, 0, stream>>>(cbox, csc, ccls, cgid, bbox2, bkey2, coff);
  nms_class_k<<<dim3(80, 4), 64, 0, stream>>>(bbox2, bkey2, coff, kbox, kkey, kcnt);
  nms_merge_k<<<4, 64, 0, stream>>>(kbox, kkey, kcnt, out);
}